// Round 18
// baseline (388.032 us; speedup 1.0000x reference)
//
#include <hip/hip_runtime.h>
#include <hip/hip_bf16.h>

// ---------------- problem constants ----------------
constexpr int Bg  = 8;       // graphs
constexpr int Nn  = 1024;    // nodes per graph
constexpr int Cc  = 256;     // channels
constexpr int Hh  = 8;       // heads
constexpr int DKh = 32;      // head dim
constexpr int Ee  = 131072;  // edges
constexpr int BNn = Bg * Nn; // 8192 total nodes
constexpr int MSPLIT = 2;    // attention m-range split
constexpr int MCH = Nn / MSPLIT;
#define EPSV 1e-5f

typedef __attribute__((ext_vector_type(8))) short bf16x8;
typedef __attribute__((ext_vector_type(4))) float f32x4;

static __device__ __forceinline__ unsigned short f2b(float v) {
    __hip_bfloat16 h = __float2bfloat16(v);
    return __builtin_bit_cast(unsigned short, h);
}
static __device__ __forceinline__ float b2f(unsigned short u) {
    unsigned int x = ((unsigned int)u) << 16;
    return __builtin_bit_cast(float, x);
}
static __device__ __forceinline__ bf16x8 ldb8(const unsigned short* p) {
    return *(const bf16x8*)p;
}

// ---------------- fused prep: xconv + wconv + hist ----------------
__global__ __launch_bounds__(256) void prep_k(
    const float* __restrict__ x, unsigned short* __restrict__ xcat,
    const float* __restrict__ Wr, const float* __restrict__ Wn,
    const float* __restrict__ Wq, const float* __restrict__ Wk,
    const float* __restrict__ Wv, const float* __restrict__ Wo,
    const float* __restrict__ W1, const float* __restrict__ W2,
    unsigned short* __restrict__ WcatT,
    unsigned short* __restrict__ WqT, unsigned short* __restrict__ WkT,
    unsigned short* __restrict__ WvT, unsigned short* __restrict__ WoT,
    unsigned short* __restrict__ W1T, unsigned short* __restrict__ W2T,
    const int* __restrict__ ei, int* __restrict__ deg)
{
    int blk = blockIdx.x;
    if (blk < 2048) {
        int i = (blk * 256 + threadIdx.x) * 4;
        float4 v = *(const float4*)(x + i);
        int r = i >> 8, c = i & 255;
        ushort4 pk;
        pk.x = f2b(v.x); pk.y = f2b(v.y); pk.z = f2b(v.z); pk.w = f2b(v.w);
        *(ushort4*)(xcat + (size_t)r * 512 + c) = pk;
    } else if (blk < 4608) {
        int idx = (blk - 2048) * 256 + threadIdx.x;
        if (idx < 131072) {                      // WcatT [256][512]
            int n = idx >> 9, k = idx & 511;
            float v = (k < 256) ? Wr[k * 256 + n] : Wn[(k - 256) * 256 + n];
            WcatT[(size_t)n * 512 + k] = f2b(v);
        } else if (idx < 393216) {               // q,k,v,o
            int l = idx - 131072;
            int wsel = l >> 16; l &= 65535;
            int n = l >> 8, kk = l & 255;
            const float* S = wsel == 0 ? Wq : wsel == 1 ? Wk : wsel == 2 ? Wv : Wo;
            unsigned short* D = wsel == 0 ? WqT : wsel == 1 ? WkT : wsel == 2 ? WvT : WoT;
            D[n * 256 + kk] = f2b(S[kk * 256 + n]);
        } else if (idx < 524288) {               // W1 [256][512] -> W1T [512][256]
            int l = idx - 393216;
            int n = l >> 8, kk = l & 255;
            W1T[l] = f2b(W1[kk * 512 + n]);
        } else {                                 // W2 [512][256] -> W2T [256][512]
            int l = idx - 524288;
            int n = l >> 9, kk = l & 511;
            W2T[l] = f2b(W2[kk * 256 + n]);
        }
    } else {
        int e = (blk - 4608) * 256 + threadIdx.x;
        atomicAdd(&deg[ei[Ee + e]], 1);
    }
}

// ---------------- CSR scan (coalesced, interleaved buckets) ----------------
__global__ __launch_bounds__(256) void scan_k(
    const int* __restrict__ deg, int* __restrict__ rowst, int* __restrict__ cursor)
{
    __shared__ int partial[256];
    int t = threadIdx.x;
    int local[32];
    int s = 0;
    #pragma unroll
    for (int i = 0; i < 32; ++i) { local[i] = deg[i * 256 + t]; s += local[i]; }
    partial[t] = s;
    __syncthreads();
    for (int off = 1; off < 256; off <<= 1) {
        int v = (t >= off) ? partial[t - off] : 0;
        __syncthreads();
        partial[t] += v;
        __syncthreads();
    }
    int base = partial[t] - s;
    #pragma unroll
    for (int i = 0; i < 32; ++i) {
        int n = i * 256 + t;
        rowst[n] = base;
        cursor[n] = base;
        base += local[i];
    }
}

__global__ __launch_bounds__(256) void place_k(
    const int* __restrict__ ei, int* __restrict__ cursor, int* __restrict__ eidx)
{
    int e = blockIdx.x * 256 + threadIdx.x;
    int s = ei[e], d = ei[Ee + e];
    int pos = atomicAdd(&cursor[d], 1);
    eidx[pos] = s;
}

// ---------------- merged gather (blocks 0..2047) + QKV GEMM (2048..5119) ----------------
__global__ __launch_bounds__(256, 4) void gather_qkv_k(
    const float* __restrict__ x, const int* __restrict__ rowst,
    const int* __restrict__ deg, const int* __restrict__ eidx,
    unsigned short* __restrict__ xcat,
    const unsigned short* __restrict__ WT,
    const float* __restrict__ bq, const float* __restrict__ bk,
    const float* __restrict__ bv,
    unsigned short* __restrict__ qb, unsigned short* __restrict__ kb,
    unsigned short* __restrict__ vTb, float qscale)
{
    __shared__ unsigned short vtile[64][40];
    int blk = blockIdx.x;

    if (blk < 2048) {
        // gather: 4 nodes per block, one 64-lane wave each
        int n = blk * 4 + (threadIdx.x >> 6);
        int c4 = (threadIdx.x & 63) * 4;
        int b0 = rowst[n], d = deg[n];
        float4 acc = {0.f, 0.f, 0.f, 0.f};
        int i = 0;
        for (; i + 4 <= d; i += 4) {
            int s0 = eidx[b0 + i], s1 = eidx[b0 + i + 1];
            int s2 = eidx[b0 + i + 2], s3 = eidx[b0 + i + 3];
            float4 a0 = *(const float4*)(x + (size_t)s0 * Cc + c4);
            float4 a1 = *(const float4*)(x + (size_t)s1 * Cc + c4);
            float4 a2 = *(const float4*)(x + (size_t)s2 * Cc + c4);
            float4 a3 = *(const float4*)(x + (size_t)s3 * Cc + c4);
            acc.x += (a0.x + a1.x) + (a2.x + a3.x);
            acc.y += (a0.y + a1.y) + (a2.y + a3.y);
            acc.z += (a0.z + a1.z) + (a2.z + a3.z);
            acc.w += (a0.w + a1.w) + (a2.w + a3.w);
        }
        for (; i < d; ++i) {
            int s = eidx[b0 + i];
            float4 a = *(const float4*)(x + (size_t)s * Cc + c4);
            acc.x += a.x; acc.y += a.y; acc.z += a.z; acc.w += a.w;
        }
        ushort4 pk;
        pk.x = f2b(acc.x); pk.y = f2b(acc.y); pk.z = f2b(acc.z); pk.w = f2b(acc.w);
        *(ushort4*)(xcat + (size_t)n * 512 + 256 + c4) = pk;
        return;
    }

    // QKV GEMM, N=768 = [q|k|v]; reads xcat low half only (lda=512, K=256)
    int qblk = blk - 2048;
    const int n0 = (qblk % 12) * 64;
    const int m0 = (qblk / 12) * 32;
    const int t = threadIdx.x;
    const int wave = t >> 6, lane = t & 63;
    const int tl = lane & 15, g = lane >> 4;
    const int wr = wave >> 1, wc = wave & 1;
    const int which = n0 >> 8;               // 0:q 1:k 2:v
    const int K = 256, lda = 512;

    f32x4 acc[2] = {};

    const unsigned short* a0 = xcat + (size_t)(m0 + wr * 16 + tl) * lda + g * 8;
    const unsigned short* b0 = WT + (size_t)(n0 + wc * 32 + tl) * K + g * 8;
    const unsigned short* b1 = b0 + (size_t)16 * K;

    for (int k0 = 0; k0 < K; k0 += 32) {
        bf16x8 af  = ldb8(a0 + k0);
        bf16x8 bf0 = ldb8(b0 + k0), bf1 = ldb8(b1 + k0);
        acc[0] = __builtin_amdgcn_mfma_f32_16x16x32_bf16(af, bf0, acc[0], 0, 0, 0);
        acc[1] = __builtin_amdgcn_mfma_f32_16x16x32_bf16(af, bf1, acc[1], 0, 0, 0);
    }

    const float* bias = which == 0 ? bq : which == 1 ? bk : bv;
    const float sc = which == 0 ? qscale : 1.f;

    if (which < 2) {
        unsigned short* dst = which == 0 ? qb : kb;
        #pragma unroll
        for (int c16 = 0; c16 < 2; ++c16)
            #pragma unroll
            for (int reg = 0; reg < 4; ++reg) {
                int row = m0 + wr * 16 + g * 4 + reg;
                int col = (n0 & 255) + wc * 32 + c16 * 16 + tl;
                dst[(size_t)row * Cc + col] = f2b((acc[c16][reg] + bias[col]) * sc);
            }
    } else {
        #pragma unroll
        for (int c16 = 0; c16 < 2; ++c16)
            #pragma unroll
            for (int reg = 0; reg < 4; ++reg) {
                int colL = wc * 32 + c16 * 16 + tl;
                int rowL = wr * 16 + g * 4 + reg;
                vtile[colL][rowL] = f2b(acc[c16][reg] + bias[(n0 & 255) + colL]);
            }
        __syncthreads();
        int clocal = t >> 2, q = t & 3;
        int colg = (n0 & 255) + clocal;
        int hh = colg >> 5, dd = colg & 31;
        int bg = m0 >> 10, nb = (m0 & 1023) + q * 8;
        ushort4 u0 = *(ushort4*)&vtile[clocal][q * 8];
        ushort4 u1 = *(ushort4*)&vtile[clocal][q * 8 + 4];
        unsigned short* dst = vTb + ((size_t)((bg * Hh + hh) * DKh + dd)) * Nn + nb;
        *(ushort4*)dst = u0;
        *(ushort4*)(dst + 4) = u1;
    }
}

// ---------------- merged attention (blocks 0..1023) + h1pre GEMM (1024..1535) ----------------
// R15/R17 measured-optimum attention body; O-partials now written as bf16
// (unnormalized partials keep relative precision; halves partial traffic).
__global__ __launch_bounds__(512, 6) void attn_h1_k(
    const unsigned short* __restrict__ q, const unsigned short* __restrict__ k,
    const unsigned short* __restrict__ vT, const float* __restrict__ sph,
    unsigned short* __restrict__ op0, unsigned short* __restrict__ op1,
    float* __restrict__ lpart,
    const unsigned short* __restrict__ xcat, const unsigned short* __restrict__ WcatT,
    const float* __restrict__ x, float* __restrict__ h1pre,
    float* __restrict__ gsum, float* __restrict__ gsq)
{
    __shared__ float Sph[16][68];
    __shared__ unsigned short Ps[Hh][16][72];
    float* csum = (float*)&Ps[0][0][0];     // [2][64], aliased (gemm branch only)
    float* csq  = csum + 128;

    const int blk = blockIdx.x;
    const int t = threadIdx.x;
    const int wave = t >> 6;
    const int lane = t & 63;
    const int tl = lane & 15, g = lane >> 4;

    if (blk < 1024) {
        // ---------- attention ----------
        const int n0 = (blk & 63) * 16;
        const int mc = (blk >> 6) & 1;
        const int b  = blk >> 7;
        const int w  = wave;

        bf16x8 qf = ldb8(q + ((size_t)(b * Nn + n0 + tl)) * Cc + w * DKh + g * 8);

        float lsum = 0.f;
        f32x4 oacc[2] = {};

        const unsigned short* kbase = k + ((size_t)(b * Nn) + tl) * Cc + w * DKh + g * 8;
        const unsigned short* vbase = vT + ((size_t)((b * Hh + w) * DKh) + tl) * Nn + g * 8;
        const float* sbase = sph + ((size_t)b * Nn + n0) * Nn;

        for (int m0 = mc * MCH; m0 < mc * MCH + MCH; m0 += 64) {
            __syncthreads();   // prev iter's Sph reads complete
            if (t < 256) {     // float4 staging, coalesced
                int r1 = t >> 4, c1 = (t & 15) * 4;
                *(float4*)&Sph[r1][c1] =
                    *(const float4*)(sbase + (size_t)r1 * Nn + m0 + c1);
            }
            __syncthreads();   // Sph ready

            f32x4 st[4];
            #pragma unroll
            for (int mg = 0; mg < 4; ++mg) {
                bf16x8 ka = ldb8(kbase + (size_t)(m0 + mg * 16) * Cc);
                f32x4 z = {0.f, 0.f, 0.f, 0.f};
                st[mg] = __builtin_amdgcn_mfma_f32_16x16x32_bf16(ka, qf, z, 0, 0, 0);
            }

            #pragma unroll
            for (int mg = 0; mg < 4; ++mg) {
                float4 sp = *(const float4*)&Sph[tl][mg * 16 + g * 4];
                float p0 = exp2f(st[mg][0] * sp.x);
                float p1 = exp2f(st[mg][1] * sp.y);
                float p2 = exp2f(st[mg][2] * sp.z);
                float p3 = exp2f(st[mg][3] * sp.w);
                lsum += (p0 + p1) + (p2 + p3);
                ushort4 pk;
                pk.x = f2b(p0); pk.y = f2b(p1); pk.z = f2b(p2); pk.w = f2b(p3);
                *(ushort4*)&Ps[w][tl][mg * 16 + g * 4] = pk;
            }

            #pragma unroll
            for (int ks = 0; ks < 2; ++ks) {
                bf16x8 pa = ldb8(&Ps[w][tl][ks * 32 + g * 8]);
                #pragma unroll
                for (int cg = 0; cg < 2; ++cg) {
                    bf16x8 vb = ldb8(vbase + (size_t)(cg * 16) * Nn + m0 + ks * 32);
                    oacc[cg] = __builtin_amdgcn_mfma_f32_16x16x32_bf16(pa, vb, oacc[cg], 0, 0, 0);
                }
            }
        }

        lsum += __shfl_xor(lsum, 16);
        lsum += __shfl_xor(lsum, 32);
        if (g == 0)
            lpart[((size_t)mc * BNn + b * Nn + n0 + tl) * Hh + w] = lsum;

        unsigned short* op = mc == 0 ? op0 : op1;
        #pragma unroll
        for (int r = 0; r < 4; ++r)
            #pragma unroll
            for (int cg = 0; cg < 2; ++cg)
                op[((size_t)(b * Nn + n0 + g * 4 + r)) * Cc + w * DKh + cg * 16 + tl]
                    = f2b(oacc[cg][r]);
        return;
    }

    // ---------- h1pre GEMM: two 32x64 tiles per block ----------
    const int half = wave >> 2;
    const int w4 = wave & 3;
    const int wr = w4 >> 1, wc = w4 & 1;
    const int tid = (blk - 1024) * 2 + half;   // 0..1023
    const int n0 = (tid & 3) * 64;
    const int m0 = (tid >> 2) * 32;
    const int K = 512, N = Cc;

    if (t < 128) { csum[t] = 0.f; csq[t] = 0.f; }
    __syncthreads();

    f32x4 acc[2] = {};

    const unsigned short* a0 = xcat + (size_t)(m0 + wr * 16 + tl) * 512 + g * 8;
    const unsigned short* b0 = WcatT + (size_t)(n0 + wc * 32 + tl) * K + g * 8;
    const unsigned short* b1 = b0 + (size_t)16 * K;

    for (int k0 = 0; k0 < K; k0 += 32) {
        bf16x8 af  = ldb8(a0 + k0);
        bf16x8 bf0 = ldb8(b0 + k0), bf1 = ldb8(b1 + k0);
        acc[0] = __builtin_amdgcn_mfma_f32_16x16x32_bf16(af, bf0, acc[0], 0, 0, 0);
        acc[1] = __builtin_amdgcn_mfma_f32_16x16x32_bf16(af, bf1, acc[1], 0, 0, 0);
    }

    #pragma unroll
    for (int c16 = 0; c16 < 2; ++c16) {
        int colL = wc * 32 + c16 * 16 + tl;
        int col  = n0 + colL;
        float ls = 0.f, lq = 0.f;
        #pragma unroll
        for (int reg = 0; reg < 4; ++reg) {
            int row = m0 + wr * 16 + g * 4 + reg;
            size_t idx = (size_t)row * N + col;
            float v = acc[c16][reg] + x[idx];
            ls += v; lq += v * v;
            h1pre[idx] = v;
        }
        atomicAdd(&csum[half * 64 + colL], ls);
        atomicAdd(&csq[half * 64 + colL],  lq);
    }
    __syncthreads();
    if (t < 128) {
        int h2 = t >> 6;
        int tid2 = (blk - 1024) * 2 + h2;
        int n0h = (tid2 & 3) * 64;
        atomicAdd(&gsum[n0h + (t & 63)], csum[t]);
        atomicAdd(&gsq[n0h + (t & 63)],  csq[t]);
    }
}

// ---------------- Wo GEMM with fused attention-combine A-path (bf16 partials) ----------------
__global__ __launch_bounds__(256, 4) void gemm_attnA_k(
    const unsigned short* __restrict__ op0, const unsigned short* __restrict__ op1,
    const float* __restrict__ lpart,       // [2][BNn][Hh]
    const unsigned short* __restrict__ WT, const float* __restrict__ bias,
    const float* __restrict__ add1, float* __restrict__ outf,
    float* __restrict__ gsum, float* __restrict__ gsq)
{
    const int K = Cc, N = Cc;
    const int t = threadIdx.x;
    const int wave = t >> 6, lane = t & 63;
    const int tl = lane & 15, g = lane >> 4;
    const int wr = wave >> 1, wc = wave & 1;
    const int m0 = blockIdx.y * 32, n0 = blockIdx.x * 64;

    __shared__ float csum[64], csq[64];
    if (t < 64) { csum[t] = 0.f; csq[t] = 0.f; }
    __syncthreads();

    f32x4 acc[2] = {};

    const int arow = m0 + wr * 16 + tl;
    const unsigned short* a0b = op0 + (size_t)arow * K + g * 8;
    const unsigned short* a1b = op1 + (size_t)arow * K + g * 8;
    const float* l0  = lpart + (size_t)arow * Hh;
    const float* l1  = lpart + ((size_t)BNn + arow) * Hh;
    const unsigned short* b0 = WT + (size_t)(n0 + wc * 32 + tl) * K + g * 8;
    const unsigned short* b1 = b0 + (size_t)16 * K;

    for (int k0 = 0; k0 < K; k0 += 32) {
        int hh = (k0 + g * 8) >> 5;            // 8-chan group lies in one head
        float inv = 1.f / (l0[hh] + l1[hh]);
        bf16x8 ua = ldb8(a0b + k0);
        bf16x8 va = ldb8(a1b + k0);
        bf16x8 af;
        #pragma unroll
        for (int j = 0; j < 8; ++j)
            af[j] = (short)f2b((b2f((unsigned short)ua[j]) +
                                b2f((unsigned short)va[j])) * inv);
        bf16x8 bf0 = ldb8(b0 + k0), bf1 = ldb8(b1 + k0);
        acc[0] = __builtin_amdgcn_mfma_f32_16x16x32_bf16(af, bf0, acc[0], 0, 0, 0);
        acc[1] = __builtin_amdgcn_mfma_f32_16x16x32_bf16(af, bf1, acc[1], 0, 0, 0);
    }

    #pragma unroll
    for (int c16 = 0; c16 < 2; ++c16) {
        int colL = wc * 32 + c16 * 16 + tl;
        int col  = n0 + colL;
        float ls = 0.f, lq = 0.f;
        #pragma unroll
        for (int reg = 0; reg < 4; ++reg) {
            int row = m0 + wr * 16 + g * 4 + reg;
            float v = acc[c16][reg] + bias[col];
            size_t idx = (size_t)row * N + col;
            v += add1[idx];
            ls += v; lq += v * v;
            outf[idx] = v;
        }
        atomicAdd(&csum[colL], ls); atomicAdd(&csq[colL], lq);
    }
    __syncthreads();
    if (t < 64) {
        atomicAdd(&gsum[n0 + t], csum[t]);
        atomicAdd(&gsq[n0 + t],  csq[t]);
    }
}

// ---------------- BN1+BN2 coefficient precompute (1 block) ----------------
// outsum[ch] = h1pre*A1[ch] + h2pre*A2[ch] + C[ch]; coef = [A1|A2|C].
__global__ __launch_bounds__(256) void bn_coef_k(
    const float* __restrict__ stats,
    const float* __restrict__ g1, const float* __restrict__ be1,
    const float* __restrict__ g2, const float* __restrict__ be2,
    float* __restrict__ coef)
{
    int ch = threadIdx.x;
    float m1 = stats[ch] * (1.f / BNn);
    float v1 = stats[256 + ch] * (1.f / BNn) - m1 * m1;
    float sc1 = rsqrtf(v1 + EPSV) * g1[ch];
    float m2 = stats[512 + ch] * (1.f / BNn);
    float v2 = stats[768 + ch] * (1.f / BNn) - m2 * m2;
    float sc2 = rsqrtf(v2 + EPSV) * g2[ch];
    coef[ch]       = sc1;
    coef[256 + ch] = sc2;
    coef[512 + ch] = be1[ch] + be2[ch] - m1 * sc1 - m2 * sc2;
}

// ---------------- MLP1 GEMM with fused BN1+BN2 A-path ----------------
// hidden = relu(outsum @ W1 + b1), outsum computed on the fly from
// h1pre/h2pre (fp32, L2-resident) + coef — deletes the bn_apply12 pass.
__global__ __launch_bounds__(256, 4) void gemm_mlp1_k(
    const float* __restrict__ h1pre, const float* __restrict__ h2pre,
    const float* __restrict__ coef,
    const unsigned short* __restrict__ WT, const float* __restrict__ bias,
    unsigned short* __restrict__ hid)
{
    const int K = Cc, N = 2 * Cc;
    const int t = threadIdx.x;
    const int wave = t >> 6, lane = t & 63;
    const int tl = lane & 15, g = lane >> 4;
    const int wr = wave >> 1, wc = wave & 1;
    const int m0 = blockIdx.y * 32, n0 = blockIdx.x * 64;

    f32x4 acc[2] = {};

    const int arow = m0 + wr * 16 + tl;
    const float* h1p = h1pre + (size_t)arow * K + g * 8;
    const float* h2p = h2pre + (size_t)arow * K + g * 8;
    const unsigned short* b0 = WT + (size_t)(n0 + wc * 32 + tl) * K + g * 8;
    const unsigned short* b1 = b0 + (size_t)16 * K;

    for (int k0 = 0; k0 < K; k0 += 32) {
        int ch = k0 + g * 8;
        float4 c1a = *(const float4*)(coef + ch);
        float4 c1b = *(const float4*)(coef + ch + 4);
        float4 c2a = *(const float4*)(coef + 256 + ch);
        float4 c2b = *(const float4*)(coef + 256 + ch + 4);
        float4 cca = *(const float4*)(coef + 512 + ch);
        float4 ccb = *(const float4*)(coef + 512 + ch + 4);
        float4 u0 = *(const float4*)(h1p + k0);
        float4 u1 = *(const float4*)(h1p + k0 + 4);
        float4 v0 = *(const float4*)(h2p + k0);
        float4 v1 = *(const float4*)(h2p + k0 + 4);
        bf16x8 af;
        af[0] = (short)f2b(u0.x * c1a.x + v0.x * c2a.x + cca.x);
        af[1] = (short)f2b(u0.y * c1a.y + v0.y * c2a.y + cca.y);
        af[2] = (short)f2b(u0.z * c1a.z + v0.z * c2a.z + cca.z);
        af[3] = (short)f2b(u0.w * c1a.w + v0.w * c2a.w + cca.w);
        af[4] = (short)f2b(u1.x * c1b.x + v1.x * c2b.x + ccb.x);
        af[5] = (short)f2b(u1.y * c1b.y + v1.y * c2b.y + ccb.y);
        af[6] = (short)f2b(u1.z * c1b.z + v1.z * c2b.z + ccb.z);
        af[7] = (short)f2b(u1.w * c1b.w + v1.w * c2b.w + ccb.w);
        bf16x8 bf0 = ldb8(b0 + k0), bf1 = ldb8(b1 + k0);
        acc[0] = __builtin_amdgcn_mfma_f32_16x16x32_bf16(af, bf0, acc[0], 0, 0, 0);
        acc[1] = __builtin_amdgcn_mfma_f32_16x16x32_bf16(af, bf1, acc[1], 0, 0, 0);
    }

    #pragma unroll
    for (int c16 = 0; c16 < 2; ++c16) {
        int col = n0 + wc * 32 + c16 * 16 + tl;
        #pragma unroll
        for (int reg = 0; reg < 4; ++reg) {
            int row = m0 + wr * 16 + g * 4 + reg;
            float v = fmaxf(acc[c16][reg] + bias[col], 0.f);
            hid[(size_t)row * N + col] = f2b(v);
        }
    }
}

// ---------------- MLP2 GEMM: out2 = hid @ W2 + b2 + outsum(recomputed), + BN3 stats ----------------
__global__ __launch_bounds__(256, 4) void gemm_mlp2_k(
    const unsigned short* __restrict__ hid, const unsigned short* __restrict__ WT,
    const float* __restrict__ bias,
    const float* __restrict__ h1pre, const float* __restrict__ h2pre,
    const float* __restrict__ coef,
    float* __restrict__ outf, float* __restrict__ gsum, float* __restrict__ gsq)
{
    const int K = 2 * Cc, N = Cc;
    const int t = threadIdx.x;
    const int wave = t >> 6, lane = t & 63;
    const int tl = lane & 15, g = lane >> 4;
    const int wr = wave >> 1, wc = wave & 1;
    const int m0 = blockIdx.y * 32, n0 = blockIdx.x * 64;

    __shared__ float csum[64], csq[64];
    if (t < 64) { csum[t] = 0.f; csq[t] = 0.f; }
    __syncthreads();

    f32x4 acc[2] = {};

    const unsigned short* a0 = hid + (size_t)(m0 + wr * 16 + tl) * K + g * 8;
    const unsigned short* b0 = WT + (size_t)(n0 + wc * 32 + tl) * K + g * 8;
    const unsigned short* b1 = b0 + (size_t)16 * K;

    for (int k0 = 0; k0 < K; k0 += 32) {
        bf16x8 af  = ldb8(a0 + k0);
        bf16x8 bf0 = ldb8(b0 + k0), bf1 = ldb8(b1 + k0);
        acc[0] = __builtin_amdgcn_mfma_f32_16x16x32_bf16(af, bf0, acc[0], 0, 0, 0);
        acc[1] = __builtin_amdgcn_mfma_f32_16x16x32_bf16(af, bf1, acc[1], 0, 0, 0);
    }

    #pragma unroll
    for (int c16 = 0; c16 < 2; ++c16) {
        int colL = wc * 32 + c16 * 16 + tl;
        int col  = n0 + colL;
        float A1 = coef[col], A2 = coef[256 + col], CC = coef[512 + col];
        float ls = 0.f, lq = 0.f;
        #pragma unroll
        for (int reg = 0; reg < 4; ++reg) {
            int row = m0 + wr * 16 + g * 4 + reg;
            size_t idx = (size_t)row * N + col;
            float res = h1pre[idx] * A1 + h2pre[idx] * A2 + CC;  // outsum recompute
            float v = acc[c16][reg] + bias[col] + res;
            ls += v; lq += v * v;
            outf[idx] = v;
        }
        atomicAdd(&csum[colL], ls); atomicAdd(&csq[colL], lq);
    }
    __syncthreads();
    if (t < 64) {
        atomicAdd(&gsum[n0 + t], csum[t]);
        atomicAdd(&gsq[n0 + t],  csq[t]);
    }
}

// ---------------- BN apply (single, float4) ----------------
__global__ __launch_bounds__(256) void bn_apply_k(
    const float* __restrict__ h, const float* __restrict__ gsum,
    const float* __restrict__ gsq, const float* __restrict__ gamma,
    const float* __restrict__ beta, float* __restrict__ outf)
{
    size_t i4 = ((size_t)blockIdx.x * 256 + threadIdx.x) * 4;
    int ch = (int)(i4 & (Cc - 1));
    float4 hv = *(const float4*)(h + i4);
    float4 sm = *(const float4*)(gsum + ch);
    float4 sq = *(const float4*)(gsq + ch);
    float4 ga = *(const float4*)(gamma + ch);
    float4 be = *(const float4*)(beta + ch);
    float4 o;
    {
        float m = sm.x * (1.f / BNn), var = sq.x * (1.f / BNn) - m * m;
        o.x = (hv.x - m) * rsqrtf(var + EPSV) * ga.x + be.x;
    }
    {
        float m = sm.y * (1.f / BNn), var = sq.y * (1.f / BNn) - m * m;
        o.y = (hv.y - m) * rsqrtf(var + EPSV) * ga.y + be.y;
    }
    {
        float m = sm.z * (1.f / BNn), var = sq.z * (1.f / BNn) - m * m;
        o.z = (hv.z - m) * rsqrtf(var + EPSV) * ga.z + be.z;
    }
    {
        float m = sm.w * (1.f / BNn), var = sq.w * (1.f / BNn) - m * m;
        o.w = (hv.w - m) * rsqrtf(var + EPSV) * ga.w + be.w;
    }
    *(float4*)(outf + i4) = o;
}

// ---------------- launch ----------------
extern "C" void kernel_launch(void* const* d_in, const int* in_sizes, int n_in,
                              void* d_out, int out_size, void* d_ws, size_t ws_size,
                              hipStream_t stream)
{
    const float* x   = (const float*)d_in[0];
    const int*   ei  = (const int*)  d_in[1];
    const float* sph = (const float*)d_in[2];
    const float* Wr  = (const float*)d_in[3];
    const float* Wn  = (const float*)d_in[4];
    const float* Wq  = (const float*)d_in[5];
    const float* bq  = (const float*)d_in[6];
    const float* Wk  = (const float*)d_in[7];
    const float* bk  = (const float*)d_in[8];
    const float* Wv  = (const float*)d_in[9];
    const float* bv  = (const float*)d_in[10];
    const float* Wo  = (const float*)d_in[11];
    const float* bo  = (const float*)d_in[12];
    const float* W1  = (const float*)d_in[13];
    const float* b1  = (const float*)d_in[14];
    const float* W2  = (const float*)d_in[15];
    const float* b2  = (const float*)d_in[16];
    const float* g1  = (const float*)d_in[17];
    const float* be1 = (const float*)d_in[18];
    const float* g2  = (const float*)d_in[19];
    const float* be2 = (const float*)d_in[20];
    const float* g3  = (const float*)d_in[21];
    const float* be3 = (const float*)d_in[22];
    float* out = (float*)d_out;

    const size_t SL = (size_t)BNn * Cc;  // 2M elements

    float* ws = (float*)d_ws;
    float* s1 = ws;                  // bf16 O-partial 0 (as ushort) ; spare
    float* s2 = s1 + SL;             // h1pre (alive through mlp2) -> out2
    float* s3 = s2 + SL;             // h2pre

    int*   deg      = (int*)(s3 + SL);          // 8192
    float* statsAll = (float*)(deg + 8192);     // 1536
    float* coef     = statsAll + 1536;          // 768: A1|A2|C
    int*   rowst    = (int*)(coef + 768);       // 8192 (+pad)
    int*   cursor   = rowst + 8256;             // 8192
    int*   eidx     = cursor + 8192;            // 131072

    unsigned short* xcat = (unsigned short*)(eidx + 131072); // [8192][512]; reused as hid
    unsigned short* qb   = xcat + 2 * SL;
    unsigned short* kb   = qb + SL;
    unsigned short* vTb  = kb + SL;
    unsigned short* hid  = xcat;

    unsigned short* WcatT = vTb + SL;         // 256x512
    unsigned short* WqT   = WcatT + 131072;   // WqT|WkT|WvT contiguous = [768][256]
    unsigned short* WkT   = WqT + 65536;
    unsigned short* WvT   = WkT + 65536;
    unsigned short* WoT   = WvT + 65536;
    unsigned short* W1T   = WoT + 65536;
    unsigned short* W2T   = W1T + 131072;
    float* lpart   = (float*)(W2T + 131072);  // [MSPLIT][BNn][Hh] fp32
    unsigned short* op0b = (unsigned short*)s1;                       // 4 MB
    unsigned short* op1b = (unsigned short*)(lpart + (size_t)MSPLIT * BNn * Hh);

    dim3 gN256(4, 256);
    dim3 gN512(8, 256);

    const float QSCALE = 0.17677669529663687f * 1.4426950408889634f;

    // 1) zero deg + all BN stats in one memset
    hipMemsetAsync(deg, 0, (8192 + 1536) * sizeof(float), stream);
    // 2) fused converts + histogram
    prep_k<<<5120, 256, 0, stream>>>(x, xcat, Wr, Wn, Wq, Wk, Wv, Wo, W1, W2,
                                     WcatT, WqT, WkT, WvT, WoT, W1T, W2T, ei, deg);
    // 3-4) CSR scan / place
    scan_k<<<1, 256, 0, stream>>>(deg, rowst, cursor);
    place_k<<<Ee / 256, 256, 0, stream>>>(ei, cursor, eidx);
    // 5) gather (xcat hi) || QKV GEMM (xcat lo -> qb,kb,vTb)  — independent
    gather_qkv_k<<<5120, 256, 0, stream>>>(x, rowst, deg, eidx, xcat,
                                           WqT, bq, bk, bv, qb, kb, vTb, QSCALE);
    // 6) attention (bf16 O-partials + lpart) || h1pre GEMM (s2 + BN1 stats)
    attn_h1_k<<<1536, 512, 0, stream>>>(qb, kb, vTb, sph, op0b, op1b, lpart,
                                        xcat, WcatT, x, s2,
                                        statsAll, statsAll + 256);
    // 7) h2pre = normalize(op0,op1,lpart) @ Wo + bo + x -> s3, + fused BN2 stats
    gemm_attnA_k<<<gN256, 256, 0, stream>>>(op0b, op1b, lpart, WoT, bo, x,
                                            s3, statsAll + 512, statsAll + 768);
    // 8) BN1/BN2 affine coefficients (replaces the bn_apply12 full pass)
    bn_coef_k<<<1, 256, 0, stream>>>(statsAll, g1, be1, g2, be2, coef);
    // 9) hidden = relu(outsum @ W1 + b1), outsum fused into A-path -> hid
    gemm_mlp1_k<<<gN512, 256, 0, stream>>>(s2, s3, coef, W1T, b1, hid);
    // 10) out2 = hid @ W2 + b2 + outsum(recomputed) -> s2, + fused BN3 stats
    gemm_mlp2_k<<<gN256, 256, 0, stream>>>(hid, W2T, b2, s2, s3, coef,
                                           s2, statsAll + 1024, statsAll + 1280);
    // 11) d_out = BN3(out2)
    bn_apply_k<<<(int)(SL / 1024), 256, 0, stream>>>(s2, statsAll + 1024,
                                                     statsAll + 1280, g3, be3, out);
}

// Round 19
// 373.106 us; speedup vs baseline: 1.0400x; 1.0400x over previous
//
#include <hip/hip_runtime.h>
#include <hip/hip_bf16.h>

// ---------------- problem constants ----------------
constexpr int Bg  = 8;       // graphs
constexpr int Nn  = 1024;    // nodes per graph
constexpr int Cc  = 256;     // channels
constexpr int Hh  = 8;       // heads
constexpr int DKh = 32;      // head dim
constexpr int Ee  = 131072;  // edges
constexpr int BNn = Bg * Nn; // 8192 total nodes
constexpr int MSPLIT = 2;    // attention m-range split
constexpr int MCH = Nn / MSPLIT;
#define EPSV 1e-5f

typedef __attribute__((ext_vector_type(8))) short bf16x8;
typedef __attribute__((ext_vector_type(4))) float f32x4;

static __device__ __forceinline__ unsigned short f2b(float v) {
    __hip_bfloat16 h = __float2bfloat16(v);
    return __builtin_bit_cast(unsigned short, h);
}
static __device__ __forceinline__ float b2f(unsigned short u) {
    unsigned int x = ((unsigned int)u) << 16;
    return __builtin_bit_cast(float, x);
}
static __device__ __forceinline__ bf16x8 ldb8(const unsigned short* p) {
    return *(const bf16x8*)p;
}

// ---------------- fused prep: xconv + wconv + hist ----------------
__global__ __launch_bounds__(256) void prep_k(
    const float* __restrict__ x, unsigned short* __restrict__ xcat,
    const float* __restrict__ Wr, const float* __restrict__ Wn,
    const float* __restrict__ Wq, const float* __restrict__ Wk,
    const float* __restrict__ Wv, const float* __restrict__ Wo,
    const float* __restrict__ W1, const float* __restrict__ W2,
    unsigned short* __restrict__ WcatT,
    unsigned short* __restrict__ WqT, unsigned short* __restrict__ WkT,
    unsigned short* __restrict__ WvT, unsigned short* __restrict__ WoT,
    unsigned short* __restrict__ W1T, unsigned short* __restrict__ W2T,
    const int* __restrict__ ei, int* __restrict__ deg)
{
    int blk = blockIdx.x;
    if (blk < 2048) {
        int i = (blk * 256 + threadIdx.x) * 4;
        float4 v = *(const float4*)(x + i);
        int r = i >> 8, c = i & 255;
        ushort4 pk;
        pk.x = f2b(v.x); pk.y = f2b(v.y); pk.z = f2b(v.z); pk.w = f2b(v.w);
        *(ushort4*)(xcat + (size_t)r * 512 + c) = pk;
    } else if (blk < 4608) {
        int idx = (blk - 2048) * 256 + threadIdx.x;
        if (idx < 131072) {                      // WcatT [256][512]
            int n = idx >> 9, k = idx & 511;
            float v = (k < 256) ? Wr[k * 256 + n] : Wn[(k - 256) * 256 + n];
            WcatT[(size_t)n * 512 + k] = f2b(v);
        } else if (idx < 393216) {               // q,k,v,o
            int l = idx - 131072;
            int wsel = l >> 16; l &= 65535;
            int n = l >> 8, kk = l & 255;
            const float* S = wsel == 0 ? Wq : wsel == 1 ? Wk : wsel == 2 ? Wv : Wo;
            unsigned short* D = wsel == 0 ? WqT : wsel == 1 ? WkT : wsel == 2 ? WvT : WoT;
            D[n * 256 + kk] = f2b(S[kk * 256 + n]);
        } else if (idx < 524288) {               // W1 [256][512] -> W1T [512][256]
            int l = idx - 393216;
            int n = l >> 8, kk = l & 255;
            W1T[l] = f2b(W1[kk * 512 + n]);
        } else {                                 // W2 [512][256] -> W2T [256][512]
            int l = idx - 524288;
            int n = l >> 9, kk = l & 511;
            W2T[l] = f2b(W2[kk * 256 + n]);
        }
    } else {
        int e = (blk - 4608) * 256 + threadIdx.x;
        atomicAdd(&deg[ei[Ee + e]], 1);
    }
}

// ---------------- CSR scan (coalesced, interleaved buckets) ----------------
__global__ __launch_bounds__(256) void scan_k(
    const int* __restrict__ deg, int* __restrict__ rowst, int* __restrict__ cursor)
{
    __shared__ int partial[256];
    int t = threadIdx.x;
    int local[32];
    int s = 0;
    #pragma unroll
    for (int i = 0; i < 32; ++i) { local[i] = deg[i * 256 + t]; s += local[i]; }
    partial[t] = s;
    __syncthreads();
    for (int off = 1; off < 256; off <<= 1) {
        int v = (t >= off) ? partial[t - off] : 0;
        __syncthreads();
        partial[t] += v;
        __syncthreads();
    }
    int base = partial[t] - s;
    #pragma unroll
    for (int i = 0; i < 32; ++i) {
        int n = i * 256 + t;
        rowst[n] = base;
        cursor[n] = base;
        base += local[i];
    }
}

__global__ __launch_bounds__(256) void place_k(
    const int* __restrict__ ei, int* __restrict__ cursor, int* __restrict__ eidx)
{
    int e = blockIdx.x * 256 + threadIdx.x;
    int s = ei[e], d = ei[Ee + e];
    int pos = atomicAdd(&cursor[d], 1);
    eidx[pos] = s;
}

// ---------------- merged gather (blocks 0..2047) + QKV GEMM (2048..5119) ----------------
__global__ __launch_bounds__(256, 4) void gather_qkv_k(
    const float* __restrict__ x, const int* __restrict__ rowst,
    const int* __restrict__ deg, const int* __restrict__ eidx,
    unsigned short* __restrict__ xcat,
    const unsigned short* __restrict__ WT,
    const float* __restrict__ bq, const float* __restrict__ bk,
    const float* __restrict__ bv,
    unsigned short* __restrict__ qb, unsigned short* __restrict__ kb,
    unsigned short* __restrict__ vTb, float qscale)
{
    __shared__ unsigned short vtile[64][40];
    int blk = blockIdx.x;

    if (blk < 2048) {
        // gather: 4 nodes per block, one 64-lane wave each
        int n = blk * 4 + (threadIdx.x >> 6);
        int c4 = (threadIdx.x & 63) * 4;
        int b0 = rowst[n], d = deg[n];
        float4 acc = {0.f, 0.f, 0.f, 0.f};
        int i = 0;
        for (; i + 4 <= d; i += 4) {
            int s0 = eidx[b0 + i], s1 = eidx[b0 + i + 1];
            int s2 = eidx[b0 + i + 2], s3 = eidx[b0 + i + 3];
            float4 a0 = *(const float4*)(x + (size_t)s0 * Cc + c4);
            float4 a1 = *(const float4*)(x + (size_t)s1 * Cc + c4);
            float4 a2 = *(const float4*)(x + (size_t)s2 * Cc + c4);
            float4 a3 = *(const float4*)(x + (size_t)s3 * Cc + c4);
            acc.x += (a0.x + a1.x) + (a2.x + a3.x);
            acc.y += (a0.y + a1.y) + (a2.y + a3.y);
            acc.z += (a0.z + a1.z) + (a2.z + a3.z);
            acc.w += (a0.w + a1.w) + (a2.w + a3.w);
        }
        for (; i < d; ++i) {
            int s = eidx[b0 + i];
            float4 a = *(const float4*)(x + (size_t)s * Cc + c4);
            acc.x += a.x; acc.y += a.y; acc.z += a.z; acc.w += a.w;
        }
        ushort4 pk;
        pk.x = f2b(acc.x); pk.y = f2b(acc.y); pk.z = f2b(acc.z); pk.w = f2b(acc.w);
        *(ushort4*)(xcat + (size_t)n * 512 + 256 + c4) = pk;
        return;
    }

    // QKV GEMM, N=768 = [q|k|v]; reads xcat low half only (lda=512, K=256)
    int qblk = blk - 2048;
    const int n0 = (qblk % 12) * 64;
    const int m0 = (qblk / 12) * 32;
    const int t = threadIdx.x;
    const int wave = t >> 6, lane = t & 63;
    const int tl = lane & 15, g = lane >> 4;
    const int wr = wave >> 1, wc = wave & 1;
    const int which = n0 >> 8;               // 0:q 1:k 2:v
    const int K = 256, lda = 512;

    f32x4 acc[2] = {};

    const unsigned short* a0 = xcat + (size_t)(m0 + wr * 16 + tl) * lda + g * 8;
    const unsigned short* b0 = WT + (size_t)(n0 + wc * 32 + tl) * K + g * 8;
    const unsigned short* b1 = b0 + (size_t)16 * K;

    for (int k0 = 0; k0 < K; k0 += 32) {
        bf16x8 af  = ldb8(a0 + k0);
        bf16x8 bf0 = ldb8(b0 + k0), bf1 = ldb8(b1 + k0);
        acc[0] = __builtin_amdgcn_mfma_f32_16x16x32_bf16(af, bf0, acc[0], 0, 0, 0);
        acc[1] = __builtin_amdgcn_mfma_f32_16x16x32_bf16(af, bf1, acc[1], 0, 0, 0);
    }

    const float* bias = which == 0 ? bq : which == 1 ? bk : bv;
    const float sc = which == 0 ? qscale : 1.f;

    if (which < 2) {
        unsigned short* dst = which == 0 ? qb : kb;
        #pragma unroll
        for (int c16 = 0; c16 < 2; ++c16)
            #pragma unroll
            for (int reg = 0; reg < 4; ++reg) {
                int row = m0 + wr * 16 + g * 4 + reg;
                int col = (n0 & 255) + wc * 32 + c16 * 16 + tl;
                dst[(size_t)row * Cc + col] = f2b((acc[c16][reg] + bias[col]) * sc);
            }
    } else {
        #pragma unroll
        for (int c16 = 0; c16 < 2; ++c16)
            #pragma unroll
            for (int reg = 0; reg < 4; ++reg) {
                int colL = wc * 32 + c16 * 16 + tl;
                int rowL = wr * 16 + g * 4 + reg;
                vtile[colL][rowL] = f2b(acc[c16][reg] + bias[(n0 & 255) + colL]);
            }
        __syncthreads();
        int clocal = t >> 2, q = t & 3;
        int colg = (n0 & 255) + clocal;
        int hh = colg >> 5, dd = colg & 31;
        int bg = m0 >> 10, nb = (m0 & 1023) + q * 8;
        ushort4 u0 = *(ushort4*)&vtile[clocal][q * 8];
        ushort4 u1 = *(ushort4*)&vtile[clocal][q * 8 + 4];
        unsigned short* dst = vTb + ((size_t)((bg * Hh + hh) * DKh + dd)) * Nn + nb;
        *(ushort4*)dst = u0;
        *(ushort4*)(dst + 4) = u1;
    }
}

// ---------------- merged attention (blocks 0..1023) + h1pre GEMM (1024..1535) ----------------
// R15/R17 measured-optimum attention body; O-partials written as bf16
// (R18-verified: halves partial traffic, attn duration unchanged, absmax same).
__global__ __launch_bounds__(512, 6) void attn_h1_k(
    const unsigned short* __restrict__ q, const unsigned short* __restrict__ k,
    const unsigned short* __restrict__ vT, const float* __restrict__ sph,
    unsigned short* __restrict__ op0, unsigned short* __restrict__ op1,
    float* __restrict__ lpart,
    const unsigned short* __restrict__ xcat, const unsigned short* __restrict__ WcatT,
    const float* __restrict__ x, float* __restrict__ h1pre,
    float* __restrict__ gsum, float* __restrict__ gsq)
{
    __shared__ float Sph[16][68];
    __shared__ unsigned short Ps[Hh][16][72];
    float* csum = (float*)&Ps[0][0][0];     // [2][64], aliased (gemm branch only)
    float* csq  = csum + 128;

    const int blk = blockIdx.x;
    const int t = threadIdx.x;
    const int wave = t >> 6;
    const int lane = t & 63;
    const int tl = lane & 15, g = lane >> 4;

    if (blk < 1024) {
        // ---------- attention ----------
        const int n0 = (blk & 63) * 16;
        const int mc = (blk >> 6) & 1;
        const int b  = blk >> 7;
        const int w  = wave;

        bf16x8 qf = ldb8(q + ((size_t)(b * Nn + n0 + tl)) * Cc + w * DKh + g * 8);

        float lsum = 0.f;
        f32x4 oacc[2] = {};

        const unsigned short* kbase = k + ((size_t)(b * Nn) + tl) * Cc + w * DKh + g * 8;
        const unsigned short* vbase = vT + ((size_t)((b * Hh + w) * DKh) + tl) * Nn + g * 8;
        const float* sbase = sph + ((size_t)b * Nn + n0) * Nn;

        for (int m0 = mc * MCH; m0 < mc * MCH + MCH; m0 += 64) {
            __syncthreads();   // prev iter's Sph reads complete
            if (t < 256) {     // float4 staging, coalesced
                int r1 = t >> 4, c1 = (t & 15) * 4;
                *(float4*)&Sph[r1][c1] =
                    *(const float4*)(sbase + (size_t)r1 * Nn + m0 + c1);
            }
            __syncthreads();   // Sph ready

            f32x4 st[4];
            #pragma unroll
            for (int mg = 0; mg < 4; ++mg) {
                bf16x8 ka = ldb8(kbase + (size_t)(m0 + mg * 16) * Cc);
                f32x4 z = {0.f, 0.f, 0.f, 0.f};
                st[mg] = __builtin_amdgcn_mfma_f32_16x16x32_bf16(ka, qf, z, 0, 0, 0);
            }

            #pragma unroll
            for (int mg = 0; mg < 4; ++mg) {
                float4 sp = *(const float4*)&Sph[tl][mg * 16 + g * 4];
                float p0 = exp2f(st[mg][0] * sp.x);
                float p1 = exp2f(st[mg][1] * sp.y);
                float p2 = exp2f(st[mg][2] * sp.z);
                float p3 = exp2f(st[mg][3] * sp.w);
                lsum += (p0 + p1) + (p2 + p3);
                ushort4 pk;
                pk.x = f2b(p0); pk.y = f2b(p1); pk.z = f2b(p2); pk.w = f2b(p3);
                *(ushort4*)&Ps[w][tl][mg * 16 + g * 4] = pk;
            }

            #pragma unroll
            for (int ks = 0; ks < 2; ++ks) {
                bf16x8 pa = ldb8(&Ps[w][tl][ks * 32 + g * 8]);
                #pragma unroll
                for (int cg = 0; cg < 2; ++cg) {
                    bf16x8 vb = ldb8(vbase + (size_t)(cg * 16) * Nn + m0 + ks * 32);
                    oacc[cg] = __builtin_amdgcn_mfma_f32_16x16x32_bf16(pa, vb, oacc[cg], 0, 0, 0);
                }
            }
        }

        lsum += __shfl_xor(lsum, 16);
        lsum += __shfl_xor(lsum, 32);
        if (g == 0)
            lpart[((size_t)mc * BNn + b * Nn + n0 + tl) * Hh + w] = lsum;

        unsigned short* op = mc == 0 ? op0 : op1;
        #pragma unroll
        for (int r = 0; r < 4; ++r)
            #pragma unroll
            for (int cg = 0; cg < 2; ++cg)
                op[((size_t)(b * Nn + n0 + g * 4 + r)) * Cc + w * DKh + cg * 16 + tl]
                    = f2b(oacc[cg][r]);
        return;
    }

    // ---------- h1pre GEMM: two 32x64 tiles per block ----------
    const int half = wave >> 2;
    const int w4 = wave & 3;
    const int wr = w4 >> 1, wc = w4 & 1;
    const int tid = (blk - 1024) * 2 + half;   // 0..1023
    const int n0 = (tid & 3) * 64;
    const int m0 = (tid >> 2) * 32;
    const int K = 512, N = Cc;

    if (t < 128) { csum[t] = 0.f; csq[t] = 0.f; }
    __syncthreads();

    f32x4 acc[2] = {};

    const unsigned short* a0 = xcat + (size_t)(m0 + wr * 16 + tl) * 512 + g * 8;
    const unsigned short* b0 = WcatT + (size_t)(n0 + wc * 32 + tl) * K + g * 8;
    const unsigned short* b1 = b0 + (size_t)16 * K;

    for (int k0 = 0; k0 < K; k0 += 32) {
        bf16x8 af  = ldb8(a0 + k0);
        bf16x8 bf0 = ldb8(b0 + k0), bf1 = ldb8(b1 + k0);
        acc[0] = __builtin_amdgcn_mfma_f32_16x16x32_bf16(af, bf0, acc[0], 0, 0, 0);
        acc[1] = __builtin_amdgcn_mfma_f32_16x16x32_bf16(af, bf1, acc[1], 0, 0, 0);
    }

    #pragma unroll
    for (int c16 = 0; c16 < 2; ++c16) {
        int colL = wc * 32 + c16 * 16 + tl;
        int col  = n0 + colL;
        float ls = 0.f, lq = 0.f;
        #pragma unroll
        for (int reg = 0; reg < 4; ++reg) {
            int row = m0 + wr * 16 + g * 4 + reg;
            size_t idx = (size_t)row * N + col;
            float v = acc[c16][reg] + x[idx];
            ls += v; lq += v * v;
            h1pre[idx] = v;
        }
        atomicAdd(&csum[half * 64 + colL], ls);
        atomicAdd(&csq[half * 64 + colL],  lq);
    }
    __syncthreads();
    if (t < 128) {
        int h2 = t >> 6;
        int tid2 = (blk - 1024) * 2 + h2;
        int n0h = (tid2 & 3) * 64;
        atomicAdd(&gsum[n0h + (t & 63)], csum[t]);
        atomicAdd(&gsq[n0h + (t & 63)],  csq[t]);
    }
}

// ---------------- MFMA GEMM, 32x64 tile, optional fused BN-stats ----------------
// TAG: 1 = mlp1 (N=512), 2 = mlp2 (K=512).
template<int TAG>
__global__ __launch_bounds__(256, 4) void gemm_mfma_k(
    const unsigned short* __restrict__ A, const unsigned short* __restrict__ WT,
    const float* __restrict__ bias, const float* __restrict__ add1,
    float* __restrict__ outf, unsigned short* __restrict__ outb,
    float* __restrict__ gsum, float* __restrict__ gsq,
    int M, int K, int lda, int N, int relu, float oscale)
{
    const int t = threadIdx.x;
    const int wave = t >> 6, lane = t & 63;
    const int tl = lane & 15, g = lane >> 4;
    const int wr = wave >> 1, wc = wave & 1;
    const int m0 = blockIdx.y * 32, n0 = blockIdx.x * 64;

    __shared__ float csum[64], csq[64];
    if (gsum) {
        if (t < 64) { csum[t] = 0.f; csq[t] = 0.f; }
        __syncthreads();
    }

    f32x4 acc[2] = {};

    const unsigned short* a0 = A  + (size_t)(m0 + wr * 16 + tl) * lda + g * 8;
    const unsigned short* b0 = WT + (size_t)(n0 + wc * 32 + tl) * K + g * 8;
    const unsigned short* b1 = b0 + (size_t)16 * K;

    for (int k0 = 0; k0 < K; k0 += 32) {
        bf16x8 af  = ldb8(a0 + k0);
        bf16x8 bf0 = ldb8(b0 + k0), bf1 = ldb8(b1 + k0);
        acc[0] = __builtin_amdgcn_mfma_f32_16x16x32_bf16(af, bf0, acc[0], 0, 0, 0);
        acc[1] = __builtin_amdgcn_mfma_f32_16x16x32_bf16(af, bf1, acc[1], 0, 0, 0);
    }

    #pragma unroll
    for (int c16 = 0; c16 < 2; ++c16) {
        int colL = wc * 32 + c16 * 16 + tl;
        int col  = n0 + colL;
        float ls = 0.f, lq = 0.f;
        #pragma unroll
        for (int reg = 0; reg < 4; ++reg) {
            int row = m0 + wr * 16 + g * 4 + reg;
            float v = acc[c16][reg];
            if (bias) v += bias[col];
            v *= oscale;
            size_t idx = (size_t)row * N + col;
            if (add1) v += add1[idx];
            ls += v; lq += v * v;
            if (relu) v = fmaxf(v, 0.f);
            if (outf) outf[idx] = v;
            if (outb) outb[idx] = f2b(v);
        }
        if (gsum) { atomicAdd(&csum[colL], ls); atomicAdd(&csq[colL], lq); }
    }
    if (gsum) {
        __syncthreads();
        if (t < 64) {
            atomicAdd(&gsum[n0 + t], csum[t]);
            atomicAdd(&gsq[n0 + t],  csq[t]);
        }
    }
}

// ---------------- Wo GEMM with fused attention-combine A-path (bf16 partials) ----------------
__global__ __launch_bounds__(256, 4) void gemm_attnA_k(
    const unsigned short* __restrict__ op0, const unsigned short* __restrict__ op1,
    const float* __restrict__ lpart,       // [2][BNn][Hh]
    const unsigned short* __restrict__ WT, const float* __restrict__ bias,
    const float* __restrict__ add1, float* __restrict__ outf,
    float* __restrict__ gsum, float* __restrict__ gsq)
{
    const int K = Cc, N = Cc;
    const int t = threadIdx.x;
    const int wave = t >> 6, lane = t & 63;
    const int tl = lane & 15, g = lane >> 4;
    const int wr = wave >> 1, wc = wave & 1;
    const int m0 = blockIdx.y * 32, n0 = blockIdx.x * 64;

    __shared__ float csum[64], csq[64];
    if (t < 64) { csum[t] = 0.f; csq[t] = 0.f; }
    __syncthreads();

    f32x4 acc[2] = {};

    const int arow = m0 + wr * 16 + tl;
    const unsigned short* a0b = op0 + (size_t)arow * K + g * 8;
    const unsigned short* a1b = op1 + (size_t)arow * K + g * 8;
    const float* l0  = lpart + (size_t)arow * Hh;
    const float* l1  = lpart + ((size_t)BNn + arow) * Hh;
    const unsigned short* b0 = WT + (size_t)(n0 + wc * 32 + tl) * K + g * 8;
    const unsigned short* b1 = b0 + (size_t)16 * K;

    for (int k0 = 0; k0 < K; k0 += 32) {
        int hh = (k0 + g * 8) >> 5;            // 8-chan group lies in one head
        float inv = 1.f / (l0[hh] + l1[hh]);
        bf16x8 ua = ldb8(a0b + k0);
        bf16x8 va = ldb8(a1b + k0);
        bf16x8 af;
        #pragma unroll
        for (int j = 0; j < 8; ++j)
            af[j] = (short)f2b((b2f((unsigned short)ua[j]) +
                                b2f((unsigned short)va[j])) * inv);
        bf16x8 bf0 = ldb8(b0 + k0), bf1 = ldb8(b1 + k0);
        acc[0] = __builtin_amdgcn_mfma_f32_16x16x32_bf16(af, bf0, acc[0], 0, 0, 0);
        acc[1] = __builtin_amdgcn_mfma_f32_16x16x32_bf16(af, bf1, acc[1], 0, 0, 0);
    }

    #pragma unroll
    for (int c16 = 0; c16 < 2; ++c16) {
        int colL = wc * 32 + c16 * 16 + tl;
        int col  = n0 + colL;
        float ls = 0.f, lq = 0.f;
        #pragma unroll
        for (int reg = 0; reg < 4; ++reg) {
            int row = m0 + wr * 16 + g * 4 + reg;
            float v = acc[c16][reg] + bias[col];
            size_t idx = (size_t)row * N + col;
            v += add1[idx];
            ls += v; lq += v * v;
            outf[idx] = v;
        }
        atomicAdd(&csum[colL], ls); atomicAdd(&csq[colL], lq);
    }
    __syncthreads();
    if (t < 64) {
        atomicAdd(&gsum[n0 + t], csum[t]);
        atomicAdd(&gsq[n0 + t],  csq[t]);
    }
}

// ---------------- BN apply (single, float4) ----------------
__global__ __launch_bounds__(256) void bn_apply_k(
    const float* __restrict__ h, const float* __restrict__ gsum,
    const float* __restrict__ gsq, const float* __restrict__ gamma,
    const float* __restrict__ beta, float* __restrict__ outf)
{
    size_t i4 = ((size_t)blockIdx.x * 256 + threadIdx.x) * 4;
    int ch = (int)(i4 & (Cc - 1));
    float4 hv = *(const float4*)(h + i4);
    float4 sm = *(const float4*)(gsum + ch);
    float4 sq = *(const float4*)(gsq + ch);
    float4 ga = *(const float4*)(gamma + ch);
    float4 be = *(const float4*)(beta + ch);
    float4 o;
    {
        float m = sm.x * (1.f / BNn), var = sq.x * (1.f / BNn) - m * m;
        o.x = (hv.x - m) * rsqrtf(var + EPSV) * ga.x + be.x;
    }
    {
        float m = sm.y * (1.f / BNn), var = sq.y * (1.f / BNn) - m * m;
        o.y = (hv.y - m) * rsqrtf(var + EPSV) * ga.y + be.y;
    }
    {
        float m = sm.z * (1.f / BNn), var = sq.z * (1.f / BNn) - m * m;
        o.z = (hv.z - m) * rsqrtf(var + EPSV) * ga.z + be.z;
    }
    {
        float m = sm.w * (1.f / BNn), var = sq.w * (1.f / BNn) - m * m;
        o.w = (hv.w - m) * rsqrtf(var + EPSV) * ga.w + be.w;
    }
    *(float4*)(outf + i4) = o;
}

// ---------------- fused BN1+BN2 apply (float4) ----------------
__global__ __launch_bounds__(256) void bn_apply12_k(
    const float* __restrict__ h1pre, const float* __restrict__ h2pre,
    const float* __restrict__ stats,
    const float* __restrict__ g1, const float* __restrict__ be1,
    const float* __restrict__ g2, const float* __restrict__ be2,
    float* __restrict__ outf, unsigned short* __restrict__ outb)
{
    size_t i4 = ((size_t)blockIdx.x * 256 + threadIdx.x) * 4;
    int ch = (int)(i4 & (Cc - 1));
    float4 h1 = *(const float4*)(h1pre + i4);
    float4 h2 = *(const float4*)(h2pre + i4);
    float4 s1m = *(const float4*)(stats + ch);
    float4 s1q = *(const float4*)(stats + 256 + ch);
    float4 s2m = *(const float4*)(stats + 512 + ch);
    float4 s2q = *(const float4*)(stats + 768 + ch);
    float4 G1 = *(const float4*)(g1 + ch),  B1 = *(const float4*)(be1 + ch);
    float4 G2 = *(const float4*)(g2 + ch),  B2 = *(const float4*)(be2 + ch);
    float4 o;
    #define BN12C(comp) { \
        float m1 = s1m.comp * (1.f / BNn), v1 = s1q.comp * (1.f / BNn) - m1 * m1; \
        float m2 = s2m.comp * (1.f / BNn), v2 = s2q.comp * (1.f / BNn) - m2 * m2; \
        o.comp = (h1.comp - m1) * rsqrtf(v1 + EPSV) * G1.comp + B1.comp \
               + (h2.comp - m2) * rsqrtf(v2 + EPSV) * G2.comp + B2.comp; }
    BN12C(x) BN12C(y) BN12C(z) BN12C(w)
    #undef BN12C
    *(float4*)(outf + i4) = o;
    ushort4 pk;
    pk.x = f2b(o.x); pk.y = f2b(o.y); pk.z = f2b(o.z); pk.w = f2b(o.w);
    *(ushort4*)(outb + i4) = pk;
}

// ---------------- launch ----------------
extern "C" void kernel_launch(void* const* d_in, const int* in_sizes, int n_in,
                              void* d_out, int out_size, void* d_ws, size_t ws_size,
                              hipStream_t stream)
{
    const float* x   = (const float*)d_in[0];
    const int*   ei  = (const int*)  d_in[1];
    const float* sph = (const float*)d_in[2];
    const float* Wr  = (const float*)d_in[3];
    const float* Wn  = (const float*)d_in[4];
    const float* Wq  = (const float*)d_in[5];
    const float* bq  = (const float*)d_in[6];
    const float* Wk  = (const float*)d_in[7];
    const float* bk  = (const float*)d_in[8];
    const float* Wv  = (const float*)d_in[9];
    const float* bv  = (const float*)d_in[10];
    const float* Wo  = (const float*)d_in[11];
    const float* bo  = (const float*)d_in[12];
    const float* W1  = (const float*)d_in[13];
    const float* b1  = (const float*)d_in[14];
    const float* W2  = (const float*)d_in[15];
    const float* b2  = (const float*)d_in[16];
    const float* g1  = (const float*)d_in[17];
    const float* be1 = (const float*)d_in[18];
    const float* g2  = (const float*)d_in[19];
    const float* be2 = (const float*)d_in[20];
    const float* g3  = (const float*)d_in[21];
    const float* be3 = (const float*)d_in[22];
    float* out = (float*)d_out;

    const size_t SL = (size_t)BNn * Cc;  // 2M elements

    float* ws = (float*)d_ws;
    float* s1 = ws;                  // bf16 op0 (as ushort) -> outsum (fp32)
    float* s2 = s1 + SL;             // h1pre (alive until bn_apply12) -> out2
    float* s3 = s2 + SL;             // h2pre

    int*   deg      = (int*)(s3 + SL);          // 8192
    float* statsAll = (float*)(deg + 8192);     // 1536
    int*   rowst    = (int*)(statsAll + 1536);  // 8192 (+pad)
    int*   cursor   = rowst + 8256;             // 8192
    int*   eidx     = cursor + 8192;            // 131072

    unsigned short* xcat = (unsigned short*)(eidx + 131072); // [8192][512]; reused as hid
    unsigned short* qb   = xcat + 2 * SL;
    unsigned short* kb   = qb + SL;                          // reused as osb
    unsigned short* vTb  = kb + SL;
    unsigned short* osb  = kb;
    unsigned short* hid  = xcat;

    unsigned short* WcatT = vTb + SL;         // 256x512
    unsigned short* WqT   = WcatT + 131072;   // WqT|WkT|WvT contiguous = [768][256]
    unsigned short* WkT   = WqT + 65536;
    unsigned short* WvT   = WkT + 65536;
    unsigned short* WoT   = WvT + 65536;
    unsigned short* W1T   = WoT + 65536;
    unsigned short* W2T   = W1T + 131072;
    float* lpart = (float*)(W2T + 131072);    // [MSPLIT][BNn][Hh] fp32
    unsigned short* op0b = (unsigned short*)s1;
    unsigned short* op1b = (unsigned short*)(lpart + (size_t)MSPLIT * BNn * Hh);

    dim3 gN256(4, 256);
    dim3 gN512(8, 256);

    const float QSCALE = 0.17677669529663687f * 1.4426950408889634f;

    // 1) zero deg + all BN stats in one memset
    hipMemsetAsync(deg, 0, (8192 + 1536) * sizeof(float), stream);
    // 2) fused converts + histogram
    prep_k<<<5120, 256, 0, stream>>>(x, xcat, Wr, Wn, Wq, Wk, Wv, Wo, W1, W2,
                                     WcatT, WqT, WkT, WvT, WoT, W1T, W2T, ei, deg);
    // 3-4) CSR scan / place
    scan_k<<<1, 256, 0, stream>>>(deg, rowst, cursor);
    place_k<<<Ee / 256, 256, 0, stream>>>(ei, cursor, eidx);
    // 5) gather (xcat hi) || QKV GEMM (xcat lo -> qb,kb,vTb)  — independent
    gather_qkv_k<<<5120, 256, 0, stream>>>(x, rowst, deg, eidx, xcat,
                                           WqT, bq, bk, bv, qb, kb, vTb, QSCALE);
    // 6) attention (bf16 O-partials + lpart) || h1pre GEMM (s2 + BN1 stats)
    attn_h1_k<<<1536, 512, 0, stream>>>(qb, kb, vTb, sph, op0b, op1b, lpart,
                                        xcat, WcatT, x, s2,
                                        statsAll, statsAll + 256);
    // 7) h2pre = normalize(op0,op1,lpart) @ Wo + bo + x -> s3, + fused BN2 stats
    gemm_attnA_k<<<gN256, 256, 0, stream>>>(op0b, op1b, lpart, WoT, bo, x,
                                            s3, statsAll + 512, statsAll + 768);
    // 8) outsum = bn1(h1pre) + bn2(h2pre) -> s1 (fp32) + osb (bf16)
    bn_apply12_k<<<(int)(SL / 1024), 256, 0, stream>>>(s2, s3, statsAll,
                                                       g1, be1, g2, be2, s1, osb);
    // 9) hidden = relu(outsum @ W1 + b1) -> hid (bf16)
    gemm_mfma_k<1><<<gN512, 256, 0, stream>>>(osb, W1T, b1, nullptr,
                                              nullptr, hid, nullptr, nullptr,
                                              BNn, Cc, Cc, 2 * Cc, 1, 1.f);
    // 10) out2 = hidden @ W2 + b2 + outsum -> s2, + fused BN3 stats
    gemm_mfma_k<2><<<gN256, 256, 0, stream>>>(hid, W2T, b2, s1,
                                              s2, nullptr, statsAll + 1024, statsAll + 1280,
                                              BNn, 2 * Cc, 2 * Cc, Cc, 0, 1.f);
    // 11) d_out = BN3(out2)
    bn_apply_k<<<(int)(SL / 1024), 256, 0, stream>>>(s2, statsAll + 1024,
                                                     statsAll + 1280, g3, be3, out);
}

// Round 20
// 371.219 us; speedup vs baseline: 1.0453x; 1.0051x over previous
//
#include <hip/hip_runtime.h>
#include <hip/hip_bf16.h>

// ---------------- problem constants ----------------
constexpr int Bg  = 8;       // graphs
constexpr int Nn  = 1024;    // nodes per graph
constexpr int Cc  = 256;     // channels
constexpr int Hh  = 8;       // heads
constexpr int DKh = 32;      // head dim
constexpr int Ee  = 131072;  // edges
constexpr int BNn = Bg * Nn; // 8192 total nodes
constexpr int MSPLIT = 2;    // attention m-range split
constexpr int MCH = Nn / MSPLIT;
#define EPSV 1e-5f

typedef __attribute__((ext_vector_type(8))) short bf16x8;
typedef __attribute__((ext_vector_type(4))) float f32x4;

static __device__ __forceinline__ unsigned short f2b(float v) {
    __hip_bfloat16 h = __float2bfloat16(v);
    return __builtin_bit_cast(unsigned short, h);
}
static __device__ __forceinline__ float b2f(unsigned short u) {
    unsigned int x = ((unsigned int)u) << 16;
    return __builtin_bit_cast(float, x);
}
static __device__ __forceinline__ bf16x8 ldb8(const unsigned short* p) {
    return *(const bf16x8*)p;
}

// ---------------- fused prep: xconv + wconv + hist ----------------
__global__ __launch_bounds__(256) void prep_k(
    const float* __restrict__ x, unsigned short* __restrict__ xcat,
    const float* __restrict__ Wr, const float* __restrict__ Wn,
    const float* __restrict__ Wq, const float* __restrict__ Wk,
    const float* __restrict__ Wv, const float* __restrict__ Wo,
    const float* __restrict__ W1, const float* __restrict__ W2,
    unsigned short* __restrict__ WcatT,
    unsigned short* __restrict__ WqT, unsigned short* __restrict__ WkT,
    unsigned short* __restrict__ WvT, unsigned short* __restrict__ WoT,
    unsigned short* __restrict__ W1T, unsigned short* __restrict__ W2T,
    const int* __restrict__ ei, int* __restrict__ deg)
{
    int blk = blockIdx.x;
    if (blk < 2048) {
        int i = (blk * 256 + threadIdx.x) * 4;
        float4 v = *(const float4*)(x + i);
        int r = i >> 8, c = i & 255;
        ushort4 pk;
        pk.x = f2b(v.x); pk.y = f2b(v.y); pk.z = f2b(v.z); pk.w = f2b(v.w);
        *(ushort4*)(xcat + (size_t)r * 512 + c) = pk;
    } else if (blk < 4608) {
        int idx = (blk - 2048) * 256 + threadIdx.x;
        if (idx < 131072) {                      // WcatT [256][512]
            int n = idx >> 9, k = idx & 511;
            float v = (k < 256) ? Wr[k * 256 + n] : Wn[(k - 256) * 256 + n];
            WcatT[(size_t)n * 512 + k] = f2b(v);
        } else if (idx < 393216) {               // q,k,v,o
            int l = idx - 131072;
            int wsel = l >> 16; l &= 65535;
            int n = l >> 8, kk = l & 255;
            const float* S = wsel == 0 ? Wq : wsel == 1 ? Wk : wsel == 2 ? Wv : Wo;
            unsigned short* D = wsel == 0 ? WqT : wsel == 1 ? WkT : wsel == 2 ? WvT : WoT;
            D[n * 256 + kk] = f2b(S[kk * 256 + n]);
        } else if (idx < 524288) {               // W1 [256][512] -> W1T [512][256]
            int l = idx - 393216;
            int n = l >> 8, kk = l & 255;
            W1T[l] = f2b(W1[kk * 512 + n]);
        } else {                                 // W2 [512][256] -> W2T [256][512]
            int l = idx - 524288;
            int n = l >> 9, kk = l & 511;
            W2T[l] = f2b(W2[kk * 256 + n]);
        }
    } else {
        int e = (blk - 4608) * 256 + threadIdx.x;
        atomicAdd(&deg[ei[Ee + e]], 1);
    }
}

// ---------------- CSR scan (coalesced, interleaved buckets) ----------------
__global__ __launch_bounds__(256) void scan_k(
    const int* __restrict__ deg, int* __restrict__ rowst, int* __restrict__ cursor)
{
    __shared__ int partial[256];
    int t = threadIdx.x;
    int local[32];
    int s = 0;
    #pragma unroll
    for (int i = 0; i < 32; ++i) { local[i] = deg[i * 256 + t]; s += local[i]; }
    partial[t] = s;
    __syncthreads();
    for (int off = 1; off < 256; off <<= 1) {
        int v = (t >= off) ? partial[t - off] : 0;
        __syncthreads();
        partial[t] += v;
        __syncthreads();
    }
    int base = partial[t] - s;
    #pragma unroll
    for (int i = 0; i < 32; ++i) {
        int n = i * 256 + t;
        rowst[n] = base;
        cursor[n] = base;
        base += local[i];
    }
}

__global__ __launch_bounds__(256) void place_k(
    const int* __restrict__ ei, int* __restrict__ cursor, int* __restrict__ eidx)
{
    int e = blockIdx.x * 256 + threadIdx.x;
    int s = ei[e], d = ei[Ee + e];
    int pos = atomicAdd(&cursor[d], 1);
    eidx[pos] = s;
}

// ---------------- merged gather (blocks 0..2047) + QKV GEMM (2048..5119) ----------------
__global__ __launch_bounds__(256, 4) void gather_qkv_k(
    const float* __restrict__ x, const int* __restrict__ rowst,
    const int* __restrict__ deg, const int* __restrict__ eidx,
    unsigned short* __restrict__ xcat,
    const unsigned short* __restrict__ WT,
    const float* __restrict__ bq, const float* __restrict__ bk,
    const float* __restrict__ bv,
    unsigned short* __restrict__ qb, unsigned short* __restrict__ kb,
    unsigned short* __restrict__ vTb, float qscale)
{
    __shared__ unsigned short vtile[64][40];
    int blk = blockIdx.x;

    if (blk < 2048) {
        // gather: 4 nodes per block, one 64-lane wave each
        int n = blk * 4 + (threadIdx.x >> 6);
        int c4 = (threadIdx.x & 63) * 4;
        int b0 = rowst[n], d = deg[n];
        float4 acc = {0.f, 0.f, 0.f, 0.f};
        int i = 0;
        for (; i + 4 <= d; i += 4) {
            int s0 = eidx[b0 + i], s1 = eidx[b0 + i + 1];
            int s2 = eidx[b0 + i + 2], s3 = eidx[b0 + i + 3];
            float4 a0 = *(const float4*)(x + (size_t)s0 * Cc + c4);
            float4 a1 = *(const float4*)(x + (size_t)s1 * Cc + c4);
            float4 a2 = *(const float4*)(x + (size_t)s2 * Cc + c4);
            float4 a3 = *(const float4*)(x + (size_t)s3 * Cc + c4);
            acc.x += (a0.x + a1.x) + (a2.x + a3.x);
            acc.y += (a0.y + a1.y) + (a2.y + a3.y);
            acc.z += (a0.z + a1.z) + (a2.z + a3.z);
            acc.w += (a0.w + a1.w) + (a2.w + a3.w);
        }
        for (; i < d; ++i) {
            int s = eidx[b0 + i];
            float4 a = *(const float4*)(x + (size_t)s * Cc + c4);
            acc.x += a.x; acc.y += a.y; acc.z += a.z; acc.w += a.w;
        }
        ushort4 pk;
        pk.x = f2b(acc.x); pk.y = f2b(acc.y); pk.z = f2b(acc.z); pk.w = f2b(acc.w);
        *(ushort4*)(xcat + (size_t)n * 512 + 256 + c4) = pk;
        return;
    }

    // QKV GEMM, N=768 = [q|k|v]; reads xcat low half only (lda=512, K=256)
    int qblk = blk - 2048;
    const int n0 = (qblk % 12) * 64;
    const int m0 = (qblk / 12) * 32;
    const int t = threadIdx.x;
    const int wave = t >> 6, lane = t & 63;
    const int tl = lane & 15, g = lane >> 4;
    const int wr = wave >> 1, wc = wave & 1;
    const int which = n0 >> 8;               // 0:q 1:k 2:v
    const int K = 256, lda = 512;

    f32x4 acc[2] = {};

    const unsigned short* a0 = xcat + (size_t)(m0 + wr * 16 + tl) * lda + g * 8;
    const unsigned short* b0 = WT + (size_t)(n0 + wc * 32 + tl) * K + g * 8;
    const unsigned short* b1 = b0 + (size_t)16 * K;

    for (int k0 = 0; k0 < K; k0 += 32) {
        bf16x8 af  = ldb8(a0 + k0);
        bf16x8 bf0 = ldb8(b0 + k0), bf1 = ldb8(b1 + k0);
        acc[0] = __builtin_amdgcn_mfma_f32_16x16x32_bf16(af, bf0, acc[0], 0, 0, 0);
        acc[1] = __builtin_amdgcn_mfma_f32_16x16x32_bf16(af, bf1, acc[1], 0, 0, 0);
    }

    const float* bias = which == 0 ? bq : which == 1 ? bk : bv;
    const float sc = which == 0 ? qscale : 1.f;

    if (which < 2) {
        unsigned short* dst = which == 0 ? qb : kb;
        #pragma unroll
        for (int c16 = 0; c16 < 2; ++c16)
            #pragma unroll
            for (int reg = 0; reg < 4; ++reg) {
                int row = m0 + wr * 16 + g * 4 + reg;
                int col = (n0 & 255) + wc * 32 + c16 * 16 + tl;
                dst[(size_t)row * Cc + col] = f2b((acc[c16][reg] + bias[col]) * sc);
            }
    } else {
        #pragma unroll
        for (int c16 = 0; c16 < 2; ++c16)
            #pragma unroll
            for (int reg = 0; reg < 4; ++reg) {
                int colL = wc * 32 + c16 * 16 + tl;
                int rowL = wr * 16 + g * 4 + reg;
                vtile[colL][rowL] = f2b(acc[c16][reg] + bias[(n0 & 255) + colL]);
            }
        __syncthreads();
        int clocal = t >> 2, q = t & 3;
        int colg = (n0 & 255) + clocal;
        int hh = colg >> 5, dd = colg & 31;
        int bg = m0 >> 10, nb = (m0 & 1023) + q * 8;
        ushort4 u0 = *(ushort4*)&vtile[clocal][q * 8];
        ushort4 u1 = *(ushort4*)&vtile[clocal][q * 8 + 4];
        unsigned short* dst = vTb + ((size_t)((bg * Hh + hh) * DKh + dd)) * Nn + nb;
        *(ushort4*)dst = u0;
        *(ushort4*)(dst + 4) = u1;
    }
}

// ---------------- merged attention (blocks 0..1023) + h1pre GEMM (1024..1535) ----------------
// R15/R17 attention body, bf16 O-partials (R18-verified). h1pre now also
// stored bf16 (stats computed in fp32 pre-rounding) — halves its traffic.
__global__ __launch_bounds__(512, 6) void attn_h1_k(
    const unsigned short* __restrict__ q, const unsigned short* __restrict__ k,
    const unsigned short* __restrict__ vT, const float* __restrict__ sph,
    unsigned short* __restrict__ op0, unsigned short* __restrict__ op1,
    float* __restrict__ lpart,
    const unsigned short* __restrict__ xcat, const unsigned short* __restrict__ WcatT,
    const float* __restrict__ x, unsigned short* __restrict__ h1preb,
    float* __restrict__ gsum, float* __restrict__ gsq)
{
    __shared__ float Sph[16][68];
    __shared__ unsigned short Ps[Hh][16][72];
    float* csum = (float*)&Ps[0][0][0];     // [2][64], aliased (gemm branch only)
    float* csq  = csum + 128;

    const int blk = blockIdx.x;
    const int t = threadIdx.x;
    const int wave = t >> 6;
    const int lane = t & 63;
    const int tl = lane & 15, g = lane >> 4;

    if (blk < 1024) {
        // ---------- attention ----------
        const int n0 = (blk & 63) * 16;
        const int mc = (blk >> 6) & 1;
        const int b  = blk >> 7;
        const int w  = wave;

        bf16x8 qf = ldb8(q + ((size_t)(b * Nn + n0 + tl)) * Cc + w * DKh + g * 8);

        float lsum = 0.f;
        f32x4 oacc[2] = {};

        const unsigned short* kbase = k + ((size_t)(b * Nn) + tl) * Cc + w * DKh + g * 8;
        const unsigned short* vbase = vT + ((size_t)((b * Hh + w) * DKh) + tl) * Nn + g * 8;
        const float* sbase = sph + ((size_t)b * Nn + n0) * Nn;

        for (int m0 = mc * MCH; m0 < mc * MCH + MCH; m0 += 64) {
            __syncthreads();   // prev iter's Sph reads complete
            if (t < 256) {     // float4 staging, coalesced
                int r1 = t >> 4, c1 = (t & 15) * 4;
                *(float4*)&Sph[r1][c1] =
                    *(const float4*)(sbase + (size_t)r1 * Nn + m0 + c1);
            }
            __syncthreads();   // Sph ready

            f32x4 st[4];
            #pragma unroll
            for (int mg = 0; mg < 4; ++mg) {
                bf16x8 ka = ldb8(kbase + (size_t)(m0 + mg * 16) * Cc);
                f32x4 z = {0.f, 0.f, 0.f, 0.f};
                st[mg] = __builtin_amdgcn_mfma_f32_16x16x32_bf16(ka, qf, z, 0, 0, 0);
            }

            #pragma unroll
            for (int mg = 0; mg < 4; ++mg) {
                float4 sp = *(const float4*)&Sph[tl][mg * 16 + g * 4];
                float p0 = exp2f(st[mg][0] * sp.x);
                float p1 = exp2f(st[mg][1] * sp.y);
                float p2 = exp2f(st[mg][2] * sp.z);
                float p3 = exp2f(st[mg][3] * sp.w);
                lsum += (p0 + p1) + (p2 + p3);
                ushort4 pk;
                pk.x = f2b(p0); pk.y = f2b(p1); pk.z = f2b(p2); pk.w = f2b(p3);
                *(ushort4*)&Ps[w][tl][mg * 16 + g * 4] = pk;
            }

            #pragma unroll
            for (int ks = 0; ks < 2; ++ks) {
                bf16x8 pa = ldb8(&Ps[w][tl][ks * 32 + g * 8]);
                #pragma unroll
                for (int cg = 0; cg < 2; ++cg) {
                    bf16x8 vb = ldb8(vbase + (size_t)(cg * 16) * Nn + m0 + ks * 32);
                    oacc[cg] = __builtin_amdgcn_mfma_f32_16x16x32_bf16(pa, vb, oacc[cg], 0, 0, 0);
                }
            }
        }

        lsum += __shfl_xor(lsum, 16);
        lsum += __shfl_xor(lsum, 32);
        if (g == 0)
            lpart[((size_t)mc * BNn + b * Nn + n0 + tl) * Hh + w] = lsum;

        unsigned short* op = mc == 0 ? op0 : op1;
        #pragma unroll
        for (int r = 0; r < 4; ++r)
            #pragma unroll
            for (int cg = 0; cg < 2; ++cg)
                op[((size_t)(b * Nn + n0 + g * 4 + r)) * Cc + w * DKh + cg * 16 + tl]
                    = f2b(oacc[cg][r]);
        return;
    }

    // ---------- h1pre GEMM: two 32x64 tiles per block ----------
    const int half = wave >> 2;
    const int w4 = wave & 3;
    const int wr = w4 >> 1, wc = w4 & 1;
    const int tid = (blk - 1024) * 2 + half;   // 0..1023
    const int n0 = (tid & 3) * 64;
    const int m0 = (tid >> 2) * 32;
    const int K = 512, N = Cc;

    if (t < 128) { csum[t] = 0.f; csq[t] = 0.f; }
    __syncthreads();

    f32x4 acc[2] = {};

    const unsigned short* a0 = xcat + (size_t)(m0 + wr * 16 + tl) * 512 + g * 8;
    const unsigned short* b0 = WcatT + (size_t)(n0 + wc * 32 + tl) * K + g * 8;
    const unsigned short* b1 = b0 + (size_t)16 * K;

    for (int k0 = 0; k0 < K; k0 += 32) {
        bf16x8 af  = ldb8(a0 + k0);
        bf16x8 bf0 = ldb8(b0 + k0), bf1 = ldb8(b1 + k0);
        acc[0] = __builtin_amdgcn_mfma_f32_16x16x32_bf16(af, bf0, acc[0], 0, 0, 0);
        acc[1] = __builtin_amdgcn_mfma_f32_16x16x32_bf16(af, bf1, acc[1], 0, 0, 0);
    }

    #pragma unroll
    for (int c16 = 0; c16 < 2; ++c16) {
        int colL = wc * 32 + c16 * 16 + tl;
        int col  = n0 + colL;
        float ls = 0.f, lq = 0.f;
        #pragma unroll
        for (int reg = 0; reg < 4; ++reg) {
            int row = m0 + wr * 16 + g * 4 + reg;
            size_t idx = (size_t)row * N + col;
            float v = acc[c16][reg] + x[idx];
            ls += v; lq += v * v;               // stats in fp32 (pre-rounding)
            h1preb[idx] = f2b(v);
        }
        atomicAdd(&csum[half * 64 + colL], ls);
        atomicAdd(&csq[half * 64 + colL],  lq);
    }
    __syncthreads();
    if (t < 128) {
        int h2 = t >> 6;
        int tid2 = (blk - 1024) * 2 + h2;
        int n0h = (tid2 & 3) * 64;
        atomicAdd(&gsum[n0h + (t & 63)], csum[t]);
        atomicAdd(&gsq[n0h + (t & 63)],  csq[t]);
    }
}

// ---------------- MFMA GEMM, 32x64 tile, optional bf16 residual + BN-stats ----------------
// TAG: 1 = mlp1 (N=512), 2 = mlp2 (K=512, bf16 residual addb = osb).
template<int TAG>
__global__ __launch_bounds__(256, 4) void gemm_mfma_k(
    const unsigned short* __restrict__ A, const unsigned short* __restrict__ WT,
    const float* __restrict__ bias, const unsigned short* __restrict__ addb,
    float* __restrict__ outf, unsigned short* __restrict__ outb,
    float* __restrict__ gsum, float* __restrict__ gsq,
    int M, int K, int lda, int N, int relu, float oscale)
{
    const int t = threadIdx.x;
    const int wave = t >> 6, lane = t & 63;
    const int tl = lane & 15, g = lane >> 4;
    const int wr = wave >> 1, wc = wave & 1;
    const int m0 = blockIdx.y * 32, n0 = blockIdx.x * 64;

    __shared__ float csum[64], csq[64];
    if (gsum) {
        if (t < 64) { csum[t] = 0.f; csq[t] = 0.f; }
        __syncthreads();
    }

    f32x4 acc[2] = {};

    const unsigned short* a0 = A  + (size_t)(m0 + wr * 16 + tl) * lda + g * 8;
    const unsigned short* b0 = WT + (size_t)(n0 + wc * 32 + tl) * K + g * 8;
    const unsigned short* b1 = b0 + (size_t)16 * K;

    for (int k0 = 0; k0 < K; k0 += 32) {
        bf16x8 af  = ldb8(a0 + k0);
        bf16x8 bf0 = ldb8(b0 + k0), bf1 = ldb8(b1 + k0);
        acc[0] = __builtin_amdgcn_mfma_f32_16x16x32_bf16(af, bf0, acc[0], 0, 0, 0);
        acc[1] = __builtin_amdgcn_mfma_f32_16x16x32_bf16(af, bf1, acc[1], 0, 0, 0);
    }

    #pragma unroll
    for (int c16 = 0; c16 < 2; ++c16) {
        int colL = wc * 32 + c16 * 16 + tl;
        int col  = n0 + colL;
        float ls = 0.f, lq = 0.f;
        #pragma unroll
        for (int reg = 0; reg < 4; ++reg) {
            int row = m0 + wr * 16 + g * 4 + reg;
            float v = acc[c16][reg];
            if (bias) v += bias[col];
            v *= oscale;
            size_t idx = (size_t)row * N + col;
            if (addb) v += b2f(addb[idx]);
            ls += v; lq += v * v;
            if (relu) v = fmaxf(v, 0.f);
            if (outf) outf[idx] = v;
            if (outb) outb[idx] = f2b(v);
        }
        if (gsum) { atomicAdd(&csum[colL], ls); atomicAdd(&csq[colL], lq); }
    }
    if (gsum) {
        __syncthreads();
        if (t < 64) {
            atomicAdd(&gsum[n0 + t], csum[t]);
            atomicAdd(&gsq[n0 + t],  csq[t]);
        }
    }
}

// ---------------- Wo GEMM with fused attention-combine A-path (bf16 partials) ----------------
// h2pre stored bf16 (stats fp32 in epilogue).
__global__ __launch_bounds__(256, 4) void gemm_attnA_k(
    const unsigned short* __restrict__ op0, const unsigned short* __restrict__ op1,
    const float* __restrict__ lpart,       // [2][BNn][Hh]
    const unsigned short* __restrict__ WT, const float* __restrict__ bias,
    const float* __restrict__ add1, unsigned short* __restrict__ h2preb,
    float* __restrict__ gsum, float* __restrict__ gsq)
{
    const int K = Cc, N = Cc;
    const int t = threadIdx.x;
    const int wave = t >> 6, lane = t & 63;
    const int tl = lane & 15, g = lane >> 4;
    const int wr = wave >> 1, wc = wave & 1;
    const int m0 = blockIdx.y * 32, n0 = blockIdx.x * 64;

    __shared__ float csum[64], csq[64];
    if (t < 64) { csum[t] = 0.f; csq[t] = 0.f; }
    __syncthreads();

    f32x4 acc[2] = {};

    const int arow = m0 + wr * 16 + tl;
    const unsigned short* a0b = op0 + (size_t)arow * K + g * 8;
    const unsigned short* a1b = op1 + (size_t)arow * K + g * 8;
    const float* l0  = lpart + (size_t)arow * Hh;
    const float* l1  = lpart + ((size_t)BNn + arow) * Hh;
    const unsigned short* b0 = WT + (size_t)(n0 + wc * 32 + tl) * K + g * 8;
    const unsigned short* b1 = b0 + (size_t)16 * K;

    for (int k0 = 0; k0 < K; k0 += 32) {
        int hh = (k0 + g * 8) >> 5;            // 8-chan group lies in one head
        float inv = 1.f / (l0[hh] + l1[hh]);
        bf16x8 ua = ldb8(a0b + k0);
        bf16x8 va = ldb8(a1b + k0);
        bf16x8 af;
        #pragma unroll
        for (int j = 0; j < 8; ++j)
            af[j] = (short)f2b((b2f((unsigned short)ua[j]) +
                                b2f((unsigned short)va[j])) * inv);
        bf16x8 bf0 = ldb8(b0 + k0), bf1 = ldb8(b1 + k0);
        acc[0] = __builtin_amdgcn_mfma_f32_16x16x32_bf16(af, bf0, acc[0], 0, 0, 0);
        acc[1] = __builtin_amdgcn_mfma_f32_16x16x32_bf16(af, bf1, acc[1], 0, 0, 0);
    }

    #pragma unroll
    for (int c16 = 0; c16 < 2; ++c16) {
        int colL = wc * 32 + c16 * 16 + tl;
        int col  = n0 + colL;
        float ls = 0.f, lq = 0.f;
        #pragma unroll
        for (int reg = 0; reg < 4; ++reg) {
            int row = m0 + wr * 16 + g * 4 + reg;
            float v = acc[c16][reg] + bias[col];
            size_t idx = (size_t)row * N + col;
            v += add1[idx];
            ls += v; lq += v * v;               // stats in fp32 (pre-rounding)
            h2preb[idx] = f2b(v);
        }
        atomicAdd(&csum[colL], ls); atomicAdd(&csq[colL], lq);
    }
    __syncthreads();
    if (t < 64) {
        atomicAdd(&gsum[n0 + t], csum[t]);
        atomicAdd(&gsq[n0 + t],  csq[t]);
    }
}

// ---------------- BN apply (single, float4) ----------------
__global__ __launch_bounds__(256) void bn_apply_k(
    const float* __restrict__ h, const float* __restrict__ gsum,
    const float* __restrict__ gsq, const float* __restrict__ gamma,
    const float* __restrict__ beta, float* __restrict__ outf)
{
    size_t i4 = ((size_t)blockIdx.x * 256 + threadIdx.x) * 4;
    int ch = (int)(i4 & (Cc - 1));
    float4 hv = *(const float4*)(h + i4);
    float4 sm = *(const float4*)(gsum + ch);
    float4 sq = *(const float4*)(gsq + ch);
    float4 ga = *(const float4*)(gamma + ch);
    float4 be = *(const float4*)(beta + ch);
    float4 o;
    {
        float m = sm.x * (1.f / BNn), var = sq.x * (1.f / BNn) - m * m;
        o.x = (hv.x - m) * rsqrtf(var + EPSV) * ga.x + be.x;
    }
    {
        float m = sm.y * (1.f / BNn), var = sq.y * (1.f / BNn) - m * m;
        o.y = (hv.y - m) * rsqrtf(var + EPSV) * ga.y + be.y;
    }
    {
        float m = sm.z * (1.f / BNn), var = sq.z * (1.f / BNn) - m * m;
        o.z = (hv.z - m) * rsqrtf(var + EPSV) * ga.z + be.z;
    }
    {
        float m = sm.w * (1.f / BNn), var = sq.w * (1.f / BNn) - m * m;
        o.w = (hv.w - m) * rsqrtf(var + EPSV) * ga.w + be.w;
    }
    *(float4*)(outf + i4) = o;
}

// ---------------- fused BN1+BN2 apply (bf16 in / bf16 out, 12 MB total) ----------------
__global__ __launch_bounds__(256) void bn_apply12_k(
    const unsigned short* __restrict__ h1preb, const unsigned short* __restrict__ h2preb,
    const float* __restrict__ stats,
    const float* __restrict__ g1, const float* __restrict__ be1,
    const float* __restrict__ g2, const float* __restrict__ be2,
    unsigned short* __restrict__ outb)
{
    size_t i4 = ((size_t)blockIdx.x * 256 + threadIdx.x) * 4;
    int ch = (int)(i4 & (Cc - 1));
    ushort4 u1 = *(const ushort4*)(h1preb + i4);
    ushort4 u2 = *(const ushort4*)(h2preb + i4);
    float4 s1m = *(const float4*)(stats + ch);
    float4 s1q = *(const float4*)(stats + 256 + ch);
    float4 s2m = *(const float4*)(stats + 512 + ch);
    float4 s2q = *(const float4*)(stats + 768 + ch);
    float4 G1 = *(const float4*)(g1 + ch),  B1 = *(const float4*)(be1 + ch);
    float4 G2 = *(const float4*)(g2 + ch),  B2 = *(const float4*)(be2 + ch);
    ushort4 pk;
    #define BN12C(comp, ucomp) { \
        float m1 = s1m.comp * (1.f / BNn), v1 = s1q.comp * (1.f / BNn) - m1 * m1; \
        float m2 = s2m.comp * (1.f / BNn), v2 = s2q.comp * (1.f / BNn) - m2 * m2; \
        float o = (b2f(u1.ucomp) - m1) * rsqrtf(v1 + EPSV) * G1.comp + B1.comp \
                + (b2f(u2.ucomp) - m2) * rsqrtf(v2 + EPSV) * G2.comp + B2.comp; \
        pk.ucomp = f2b(o); }
    BN12C(x, x) BN12C(y, y) BN12C(z, z) BN12C(w, w)
    #undef BN12C
    *(ushort4*)(outb + i4) = pk;
}

// ---------------- launch ----------------
extern "C" void kernel_launch(void* const* d_in, const int* in_sizes, int n_in,
                              void* d_out, int out_size, void* d_ws, size_t ws_size,
                              hipStream_t stream)
{
    const float* x   = (const float*)d_in[0];
    const int*   ei  = (const int*)  d_in[1];
    const float* sph = (const float*)d_in[2];
    const float* Wr  = (const float*)d_in[3];
    const float* Wn  = (const float*)d_in[4];
    const float* Wq  = (const float*)d_in[5];
    const float* bq  = (const float*)d_in[6];
    const float* Wk  = (const float*)d_in[7];
    const float* bk  = (const float*)d_in[8];
    const float* Wv  = (const float*)d_in[9];
    const float* bv  = (const float*)d_in[10];
    const float* Wo  = (const float*)d_in[11];
    const float* bo  = (const float*)d_in[12];
    const float* W1  = (const float*)d_in[13];
    const float* b1  = (const float*)d_in[14];
    const float* W2  = (const float*)d_in[15];
    const float* b2  = (const float*)d_in[16];
    const float* g1  = (const float*)d_in[17];
    const float* be1 = (const float*)d_in[18];
    const float* g2  = (const float*)d_in[19];
    const float* be2 = (const float*)d_in[20];
    const float* g3  = (const float*)d_in[21];
    const float* be3 = (const float*)d_in[22];
    float* out = (float*)d_out;

    const size_t SL = (size_t)BNn * Cc;  // 2M elements

    float* ws = (float*)d_ws;
    float* s1 = ws;                  // op0b (bf16, 4MB)
    float* s2 = s1 + SL;             // h1preb (bf16) then out2 (fp32)
    float* s3 = s2 + SL;             // h2preb (bf16)

    int*   deg      = (int*)(s3 + SL);          // 8192
    float* statsAll = (float*)(deg + 8192);     // 1536
    int*   rowst    = (int*)(statsAll + 1536);  // 8192 (+pad)
    int*   cursor   = rowst + 8256;             // 8192
    int*   eidx     = cursor + 8192;            // 131072

    unsigned short* xcat = (unsigned short*)(eidx + 131072); // [8192][512]; reused as hid
    unsigned short* qb   = xcat + 2 * SL;
    unsigned short* kb   = qb + SL;                          // reused as osb
    unsigned short* vTb  = kb + SL;
    unsigned short* osb  = kb;
    unsigned short* hid  = xcat;

    unsigned short* WcatT = vTb + SL;         // 256x512
    unsigned short* WqT   = WcatT + 131072;   // WqT|WkT|WvT contiguous = [768][256]
    unsigned short* WkT   = WqT + 65536;
    unsigned short* WvT   = WkT + 65536;
    unsigned short* WoT   = WvT + 65536;
    unsigned short* W1T   = WoT + 65536;
    unsigned short* W2T   = W1T + 131072;
    float* lpart = (float*)(W2T + 131072);    // [MSPLIT][BNn][Hh] fp32
    unsigned short* op0b   = (unsigned short*)s1;
    unsigned short* op1b   = (unsigned short*)(lpart + (size_t)MSPLIT * BNn * Hh);
    unsigned short* h1preb = (unsigned short*)s2;   // 4MB of s2; dead before out2
    unsigned short* h2preb = (unsigned short*)s3;

    dim3 gN256(4, 256);
    dim3 gN512(8, 256);

    const float QSCALE = 0.17677669529663687f * 1.4426950408889634f;

    // 1) zero deg + all BN stats in one memset
    hipMemsetAsync(deg, 0, (8192 + 1536) * sizeof(float), stream);
    // 2) fused converts + histogram
    prep_k<<<5120, 256, 0, stream>>>(x, xcat, Wr, Wn, Wq, Wk, Wv, Wo, W1, W2,
                                     WcatT, WqT, WkT, WvT, WoT, W1T, W2T, ei, deg);
    // 3-4) CSR scan / place
    scan_k<<<1, 256, 0, stream>>>(deg, rowst, cursor);
    place_k<<<Ee / 256, 256, 0, stream>>>(ei, cursor, eidx);
    // 5) gather (xcat hi) || QKV GEMM (xcat lo -> qb,kb,vTb)  — independent
    gather_qkv_k<<<5120, 256, 0, stream>>>(x, rowst, deg, eidx, xcat,
                                           WqT, bq, bk, bv, qb, kb, vTb, QSCALE);
    // 6) attention (bf16 O-partials + lpart) || h1pre GEMM (bf16 + BN1 stats)
    attn_h1_k<<<1536, 512, 0, stream>>>(qb, kb, vTb, sph, op0b, op1b, lpart,
                                        xcat, WcatT, x, h1preb,
                                        statsAll, statsAll + 256);
    // 7) h2pre = normalize(op0,op1,lpart) @ Wo + bo + x -> bf16, + BN2 stats
    gemm_attnA_k<<<gN256, 256, 0, stream>>>(op0b, op1b, lpart, WoT, bo, x,
                                            h2preb, statsAll + 512, statsAll + 768);
    // 8) osb = bn1(h1pre) + bn2(h2pre)   (bf16 in/out, 12 MB pass)
    bn_apply12_k<<<(int)(SL / 1024), 256, 0, stream>>>(h1preb, h2preb, statsAll,
                                                       g1, be1, g2, be2, osb);
    // 9) hidden = relu(osb @ W1 + b1) -> hid (bf16)
    gemm_mfma_k<1><<<gN512, 256, 0, stream>>>(osb, W1T, b1, nullptr,
                                              nullptr, hid, nullptr, nullptr,
                                              BNn, Cc, Cc, 2 * Cc, 1, 1.f);
    // 10) out2 = hid @ W2 + b2 + osb(residual, bf16) -> s2 fp32, + BN3 stats
    gemm_mfma_k<2><<<gN256, 256, 0, stream>>>(hid, W2T, b2, osb,
                                              s2, nullptr, statsAll + 1024, statsAll + 1280,
                                              BNn, 2 * Cc, 2 * Cc, Cc, 0, 1.f);
    // 11) d_out = BN3(out2)
    bn_apply_k<<<(int)(SL / 1024), 256, 0, stream>>>(s2, statsAll + 1024,
                                                     statsAll + 1280, g3, be3, out);
}